// Round 4
// baseline (608.848 us; speedup 1.0000x reference)
//
#include <hip/hip_runtime.h>
#include <math.h>

#define NLAYER 2
#define DMODEL 256
#define DINNER 512
#define DSTATE 16
#define DTRANK 16
#define DCONV  4
#define BB     4
#define LL     2048
#define BL     (BB*LL)
#define NCHUNK 64
#define LC     (LL/NCHUNK)          // 32
#define NREC   (BB*DINNER*DSTATE)   // 32768
#define XTOK   16                   // tokens per k_xpd block

__device__ __forceinline__ float sigmoidf_(float x) { return 1.0f / (1.0f + __expf(-x)); }

// ---------------- embedding gather ----------------
__global__ void k_embed(const int* __restrict__ ids, const float* __restrict__ emb,
                        float* __restrict__ x) {
    int bl = blockIdx.x;
    int d  = threadIdx.x;
    int id = ids[bl];
    x[(size_t)bl * DMODEL + d] = emb[(size_t)id * DMODEL + d];
}

// ---------------- fp32 tiled GEMM: C[M,N] = A[M,K] @ B[K,N] ----------------
__global__ __launch_bounds__(256) void k_sgemm(const float* __restrict__ A,
                                               const float* __restrict__ B,
                                               float* __restrict__ C,
                                               int M, int N, int K) {
    const int tid = threadIdx.x;
    const int tx = tid & 15, ty = tid >> 4;
    const int m0 = blockIdx.y * 64, n0 = blockIdx.x * 64;
    __shared__ float As[16][64];
    __shared__ float Bs[16][64];
    float acc[4][4] = {};
    const int ar = tid >> 2;
    const int ak = (tid & 3) * 4;
    const int bk = tid >> 4;
    const int bn = (tid & 15) * 4;
    for (int kk = 0; kk < K; kk += 16) {
        float4 av = *(const float4*)&A[(size_t)(m0 + ar) * K + kk + ak];
        float4 bv = *(const float4*)&B[(size_t)(kk + bk) * N + n0 + bn];
        As[ak + 0][ar] = av.x; As[ak + 1][ar] = av.y;
        As[ak + 2][ar] = av.z; As[ak + 3][ar] = av.w;
        *(float4*)&Bs[bk][bn] = bv;
        __syncthreads();
#pragma unroll
        for (int k = 0; k < 16; ++k) {
            float4 a = *(const float4*)&As[k][ty * 4];
            float4 b = *(const float4*)&Bs[k][tx * 4];
            float a4[4] = {a.x, a.y, a.z, a.w};
            float b4[4] = {b.x, b.y, b.z, b.w};
#pragma unroll
            for (int i = 0; i < 4; ++i)
#pragma unroll
                for (int j = 0; j < 4; ++j) acc[i][j] += a4[i] * b4[j];
        }
        __syncthreads();
    }
#pragma unroll
    for (int i = 0; i < 4; ++i) {
        float4 o = make_float4(acc[i][0], acc[i][1], acc[i][2], acc[i][3]);
        *(float4*)&C[(size_t)(m0 + ty * 4 + i) * N + n0 + tx * 4] = o;
    }
}

// ---------------- depthwise causal conv (D_CONV=4) + bias + SiLU ----------------
__global__ void k_conv_silu(const float* __restrict__ xz, const float* __restrict__ cw,
                            const float* __restrict__ cb, float* __restrict__ u) {
    int idx = blockIdx.x * blockDim.x + threadIdx.x;
    int c  = idx & (DINNER - 1);
    int bl = idx >> 9;
    int l  = bl & (LL - 1);
    float acc = cb[c];
#pragma unroll
    for (int k = 0; k < DCONV; ++k) {
        int t = l - (DCONV - 1) + k;
        if (t >= 0) acc += cw[c * DCONV + k] * xz[(size_t)(bl - (DCONV - 1) + k) * 2 * DINNER + c];
    }
    u[(size_t)idx] = acc * sigmoidf_(acc);
}

// ---------------- fused x_proj + delta: all-lane K-sliced GEMV + shfl reduce ----------------
// block = 256 threads = 16 tokens x 16 K-slices (32 wide each); grid = BL/16.
__global__ __launch_bounds__(256) void k_xpd(const float* __restrict__ u,
                                             const float* __restrict__ w_xp,
                                             const float* __restrict__ w_dt,
                                             const float* __restrict__ b_dt,
                                             float* __restrict__ Bm,
                                             float* __restrict__ Cm,
                                             float* __restrict__ delta) {
    const int tid = threadIdx.x;
    const int m   = tid >> 4;      // token within block
    const int s   = tid & 15;      // K-slice
    const int bl0 = blockIdx.x * XTOK;
    const int bl  = bl0 + m;
    __shared__ float dts[XTOK][DTRANK];

    // stage this thread's 32-float u slice in registers
    float ur[32];
    const float* up = &u[(size_t)bl * DINNER + s * 32];
#pragma unroll
    for (int q = 0; q < 8; ++q) {
        float4 v = *(const float4*)&up[q * 4];
        ur[q*4+0] = v.x; ur[q*4+1] = v.y; ur[q*4+2] = v.z; ur[q*4+3] = v.w;
    }

    float acc[48] = {};
#pragma unroll 4
    for (int i = 0; i < 32; ++i) {
        const float* wr = &w_xp[(s * 32 + i) * 48];
        const float uv = ur[i];
#pragma unroll
        for (int q = 0; q < 12; ++q) {
            float4 w4 = *(const float4*)&wr[q * 4];
            acc[q*4+0] = fmaf(uv, w4.x, acc[q*4+0]);
            acc[q*4+1] = fmaf(uv, w4.y, acc[q*4+1]);
            acc[q*4+2] = fmaf(uv, w4.z, acc[q*4+2]);
            acc[q*4+3] = fmaf(uv, w4.w, acc[q*4+3]);
        }
    }
    // butterfly reduce across the 16 K-slice lanes
#pragma unroll
    for (int off = 8; off >= 1; off >>= 1) {
#pragma unroll
        for (int j = 0; j < 48; ++j) acc[j] += __shfl_xor(acc[j], off, 16);
    }
    // lane s owns outputs j = 3s..3s+2  (16*3 == 48)
#pragma unroll
    for (int q = 0; q < 3; ++q) {
        int j = s * 3 + q;
        float v = acc[j];
        if (j < 16)      dts[m][j] = v;
        else if (j < 32) Bm[(size_t)bl * DSTATE + (j - 16)] = v;
        else             Cm[(size_t)bl * DSTATE + (j - 32)] = v;
    }
    __syncthreads();

    // phase 2: delta = softplus(dt @ w_dt + b_dt); thread: 4 channels x 8 tokens
    const int c0 = (tid & 127) * 4;
    const int mb = (tid >> 7) * 8;
    float4 bd = *(const float4*)&b_dt[c0];
    float a0[8], a1[8], a2[8], a3[8];
#pragma unroll
    for (int t = 0; t < 8; ++t) { a0[t] = bd.x; a1[t] = bd.y; a2[t] = bd.z; a3[t] = bd.w; }
#pragma unroll
    for (int r = 0; r < DTRANK; ++r) {
        float4 w4 = *(const float4*)&w_dt[r * DINNER + c0];
#pragma unroll
        for (int t = 0; t < 8; ++t) {
            float f = dts[mb + t][r];
            a0[t] = fmaf(f, w4.x, a0[t]);
            a1[t] = fmaf(f, w4.y, a1[t]);
            a2[t] = fmaf(f, w4.z, a2[t]);
            a3[t] = fmaf(f, w4.w, a3[t]);
        }
    }
#pragma unroll
    for (int t = 0; t < 8; ++t) {
        float4 o;
        o.x = (a0[t] > 20.f) ? a0[t] : log1pf(__expf(a0[t]));
        o.y = (a1[t] > 20.f) ? a1[t] : log1pf(__expf(a1[t]));
        o.z = (a2[t] > 20.f) ? a2[t] : log1pf(__expf(a2[t]));
        o.w = (a3[t] > 20.f) ? a3[t] : log1pf(__expf(a3[t]));
        *(float4*)&delta[(size_t)(bl0 + mb + t) * DINNER + c0] = o;
    }
}

// ---------------- chunked selective scan, per-channel 16-state-in-registers ----------------
__global__ __launch_bounds__(256) void k_scan_a(const float* __restrict__ delta,
                                                const float* __restrict__ u,
                                                const float* __restrict__ Bm,
                                                const float* __restrict__ A_log,
                                                float* __restrict__ aprod,
                                                float* __restrict__ hend) {
    const int tid = threadIdx.x;
    const int bid = blockIdx.x;
    const int chalf = bid & 1;
    const int k = (bid >> 1) & (NCHUNK - 1);
    const int b = bid >> 7;
    const int c = chalf * 256 + tid;
    const int bl0 = b * LL + k * LC;

    __shared__ float Bs[LC * DSTATE];
    for (int i = tid; i < LC * DSTATE; i += 256) Bs[i] = Bm[(size_t)bl0 * DSTATE + i];
    __syncthreads();

    float Ac[DSTATE];
#pragma unroll
    for (int q = 0; q < 4; ++q) {
        float4 a = *(const float4*)&A_log[c * DSTATE + q * 4];
        Ac[q * 4 + 0] = -__expf(a.x); Ac[q * 4 + 1] = -__expf(a.y);
        Ac[q * 4 + 2] = -__expf(a.z); Ac[q * 4 + 3] = -__expf(a.w);
    }

    float h[DSTATE] = {};
    float ap[DSTATE];
#pragma unroll
    for (int n = 0; n < DSTATE; ++n) ap[n] = 1.f;

    float dlt = delta[(size_t)bl0 * DINNER + c];
    float uu  = u[(size_t)bl0 * DINNER + c];
    for (int t = 0; t < LC; ++t) {
        float dlt2 = 0.f, uu2 = 0.f;
        if (t + 1 < LC) {
            dlt2 = delta[(size_t)(bl0 + t + 1) * DINNER + c];
            uu2  = u[(size_t)(bl0 + t + 1) * DINNER + c];
        }
        const float w = dlt * uu;
        const float4* Bs4 = (const float4*)&Bs[t * DSTATE];
        float4 b0 = Bs4[0], b1 = Bs4[1], b2 = Bs4[2], b3 = Bs4[3];
        float bv[DSTATE] = {b0.x, b0.y, b0.z, b0.w, b1.x, b1.y, b1.z, b1.w,
                            b2.x, b2.y, b2.z, b2.w, b3.x, b3.y, b3.z, b3.w};
#pragma unroll
        for (int n = 0; n < DSTATE; ++n) {
            float dA = __expf(dlt * Ac[n]);
            ap[n] *= dA;
            h[n] = fmaf(dA, h[n], w * bv[n]);
        }
        dlt = dlt2; uu = uu2;
    }
    size_t base = ((size_t)(k * BB + b) * DINNER + c) * DSTATE;
#pragma unroll
    for (int q = 0; q < 4; ++q) {
        *(float4*)&aprod[base + q * 4] = make_float4(ap[q*4], ap[q*4+1], ap[q*4+2], ap[q*4+3]);
        *(float4*)&hend[base + q * 4]  = make_float4(h[q*4],  h[q*4+1],  h[q*4+2],  h[q*4+3]);
    }
}

// Pass B: serial combine across chunks (one thread per (b,c,n)).
// NOTE: hstart may alias aprod (read-before-write order below).
__global__ __launch_bounds__(256) void k_scan_b(const float* __restrict__ aprod,
                                                const float* __restrict__ hend,
                                                float* __restrict__ hstart) {
    int i = blockIdx.x * 256 + threadIdx.x;
    float h = 0.f;
#pragma unroll 4
    for (int k = 0; k < NCHUNK; ++k) {
        size_t idx = (size_t)k * NREC + i;
        float a = aprod[idx];
        float e = hend[idx];
        hstart[idx] = h;
        h = fmaf(a, h, e);
    }
}

// Pass C: re-scan chunk from hstart, emit gated output.
__global__ __launch_bounds__(256) void k_scan_c(const float* __restrict__ delta,
                                                const float* __restrict__ u,
                                                const float* __restrict__ xz,
                                                const float* __restrict__ Bm,
                                                const float* __restrict__ Cm,
                                                const float* __restrict__ A_log,
                                                const float* __restrict__ Dp,
                                                const float* __restrict__ hstart,
                                                float* __restrict__ y) {
    const int tid = threadIdx.x;
    const int bid = blockIdx.x;
    const int chalf = bid & 1;
    const int k = (bid >> 1) & (NCHUNK - 1);
    const int b = bid >> 7;
    const int c = chalf * 256 + tid;
    const int bl0 = b * LL + k * LC;

    __shared__ float Bs[LC * DSTATE];
    __shared__ float Cs[LC * DSTATE];
    for (int i = tid; i < LC * DSTATE; i += 256) {
        Bs[i] = Bm[(size_t)bl0 * DSTATE + i];
        Cs[i] = Cm[(size_t)bl0 * DSTATE + i];
    }
    __syncthreads();

    float Ac[DSTATE];
#pragma unroll
    for (int q = 0; q < 4; ++q) {
        float4 a = *(const float4*)&A_log[c * DSTATE + q * 4];
        Ac[q * 4 + 0] = -__expf(a.x); Ac[q * 4 + 1] = -__expf(a.y);
        Ac[q * 4 + 2] = -__expf(a.z); Ac[q * 4 + 3] = -__expf(a.w);
    }
    const float Dc = Dp[c];

    float h[DSTATE];
    size_t hbase = ((size_t)(k * BB + b) * DINNER + c) * DSTATE;
#pragma unroll
    for (int q = 0; q < 4; ++q) {
        float4 hv = *(const float4*)&hstart[hbase + q * 4];
        h[q*4] = hv.x; h[q*4+1] = hv.y; h[q*4+2] = hv.z; h[q*4+3] = hv.w;
    }

    float dlt = delta[(size_t)bl0 * DINNER + c];
    float uu  = u[(size_t)bl0 * DINNER + c];
    float rr  = xz[(size_t)bl0 * 2 * DINNER + DINNER + c];
    for (int t = 0; t < LC; ++t) {
        float dlt2 = 0.f, uu2 = 0.f, rr2 = 0.f;
        if (t + 1 < LC) {
            dlt2 = delta[(size_t)(bl0 + t + 1) * DINNER + c];
            uu2  = u[(size_t)(bl0 + t + 1) * DINNER + c];
            rr2  = xz[(size_t)(bl0 + t + 1) * 2 * DINNER + DINNER + c];
        }
        const float w = dlt * uu;
        const float4* Bs4 = (const float4*)&Bs[t * DSTATE];
        float4 b0 = Bs4[0], b1 = Bs4[1], b2 = Bs4[2], b3 = Bs4[3];
        float bv[DSTATE] = {b0.x, b0.y, b0.z, b0.w, b1.x, b1.y, b1.z, b1.w,
                            b2.x, b2.y, b2.z, b2.w, b3.x, b3.y, b3.z, b3.w};
        const float4* Cs4 = (const float4*)&Cs[t * DSTATE];
        float4 c0 = Cs4[0], c1 = Cs4[1], c2 = Cs4[2], c3 = Cs4[3];
        float cv[DSTATE] = {c0.x, c0.y, c0.z, c0.w, c1.x, c1.y, c1.z, c1.w,
                            c2.x, c2.y, c2.z, c2.w, c3.x, c3.y, c3.z, c3.w};
        float s0 = 0.f, s1 = 0.f, s2 = 0.f, s3 = 0.f;
#pragma unroll
        for (int n = 0; n < DSTATE; n += 4) {
            float dA0 = __expf(dlt * Ac[n+0]);
            float dA1 = __expf(dlt * Ac[n+1]);
            float dA2 = __expf(dlt * Ac[n+2]);
            float dA3 = __expf(dlt * Ac[n+3]);
            h[n+0] = fmaf(dA0, h[n+0], w * bv[n+0]);
            h[n+1] = fmaf(dA1, h[n+1], w * bv[n+1]);
            h[n+2] = fmaf(dA2, h[n+2], w * bv[n+2]);
            h[n+3] = fmaf(dA3, h[n+3], w * bv[n+3]);
            s0 = fmaf(h[n+0], cv[n+0], s0);
            s1 = fmaf(h[n+1], cv[n+1], s1);
            s2 = fmaf(h[n+2], cv[n+2], s2);
            s3 = fmaf(h[n+3], cv[n+3], s3);
        }
        float yv = (s0 + s1) + (s2 + s3) + uu * Dc;
        y[(size_t)(bl0 + t) * DINNER + c] = yv * (rr * sigmoidf_(rr));
        dlt = dlt2; uu = uu2; rr = rr2;
    }
}

extern "C" void kernel_launch(void* const* d_in, const int* in_sizes, int n_in,
                              void* d_out, int out_size, void* d_ws, size_t ws_size,
                              hipStream_t stream) {
    const int*   ids   = (const int*)d_in[0];
    const float* emb   = (const float*)d_in[1];
    const float* w_in  = (const float*)d_in[2];
    const float* cw    = (const float*)d_in[3];
    const float* cb    = (const float*)d_in[4];
    const float* w_xp  = (const float*)d_in[5];
    const float* w_dt  = (const float*)d_in[6];
    const float* b_dt  = (const float*)d_in[7];
    const float* A_log = (const float*)d_in[8];
    const float* Dp    = (const float*)d_in[9];
    const float* w_out = (const float*)d_in[10];
    float* out = (float*)d_out;

    float* ws = (float*)d_ws;
    float* x   = ws;                              // BL*256 = 2.097M floats
    float* xz  = x  + (size_t)BL * DMODEL;        // BL*1024
    float* u   = xz + (size_t)BL * 2 * DINNER;    // BL*512
    float* Bm  = u  + (size_t)BL * DINNER;        // BL*16
    float* Cm  = Bm + (size_t)BL * DSTATE;        // BL*16
    float* dlt = Cm + (size_t)BL * DSTATE;        // BL*512
    float* y   = dlt + (size_t)BL * DINNER;       // BL*512
    float* hend = y + (size_t)BL * DINNER;        // NCHUNK*NREC = 2.097M
    // aprod overlays x (dead during scan); hstart aliases aprod (scan_b is
    // read-before-write per element).  NCHUNK*NREC == BL*DMODEL exactly.
    float* aprod  = x;
    float* hstart = aprod;

    k_embed<<<BL, DMODEL, 0, stream>>>(ids, emb, x);

    for (int l = 0; l < NLAYER; ++l) {
        dim3 g1(2 * DINNER / 64, BL / 64);
        k_sgemm<<<g1, 256, 0, stream>>>(x, w_in + (size_t)l * DMODEL * 2 * DINNER, xz,
                                        BL, 2 * DINNER, DMODEL);
        k_conv_silu<<<(BL * DINNER) / 256, 256, 0, stream>>>(
            xz, cw + l * DINNER * DCONV, cb + l * DINNER, u);
        k_xpd<<<BL / XTOK, 256, 0, stream>>>(u, w_xp + (size_t)l * DINNER * 48,
                                             w_dt + (size_t)l * DTRANK * DINNER,
                                             b_dt + (size_t)l * DINNER, Bm, Cm, dlt);
        const float* Al = A_log + (size_t)l * DINNER * DSTATE;
        k_scan_a<<<BB * NCHUNK * 2, 256, 0, stream>>>(dlt, u, Bm, Al, aprod, hend);
        k_scan_b<<<NREC / 256, 256, 0, stream>>>(aprod, hend, hstart);
        k_scan_c<<<BB * NCHUNK * 2, 256, 0, stream>>>(dlt, u, xz, Bm, Cm, Al,
                                                      Dp + (size_t)l * DINNER, hstart, y);
        float* dst = (l == NLAYER - 1) ? out : x;
        dim3 g2(DMODEL / 64, BL / 64);
        k_sgemm<<<g2, 256, 0, stream>>>(y, w_out + (size_t)l * DINNER * DMODEL, dst,
                                        BL, DMODEL, DINNER);
    }
}

// Round 5
// 477.359 us; speedup vs baseline: 1.2755x; 1.2755x over previous
//
#include <hip/hip_runtime.h>
#include <math.h>

#define NLAYER 2
#define DMODEL 256
#define DINNER 512
#define DSTATE 16
#define DTRANK 16
#define DCONV  4
#define BB     4
#define LL     2048
#define BL     (BB*LL)
#define NCHUNK 64
#define LC     (LL/NCHUNK)          // 32
#define NREC   (BB*DINNER*DSTATE)   // 32768

__device__ __forceinline__ float sigmoidf_(float x) { return 1.0f / (1.0f + __expf(-x)); }

// ---------------- embedding gather ----------------
__global__ void k_embed(const int* __restrict__ ids, const float* __restrict__ emb,
                        float* __restrict__ x) {
    int bl = blockIdx.x;
    int d  = threadIdx.x;
    int id = ids[bl];
    x[(size_t)bl * DMODEL + d] = emb[(size_t)id * DMODEL + d];
}

// ---------------- fp32 tiled GEMM: C[M,N] = A[M,K] @ B[K,N] ----------------
__global__ __launch_bounds__(256) void k_sgemm(const float* __restrict__ A,
                                               const float* __restrict__ B,
                                               float* __restrict__ C,
                                               int M, int N, int K) {
    const int tid = threadIdx.x;
    const int tx = tid & 15, ty = tid >> 4;
    const int m0 = blockIdx.y * 64, n0 = blockIdx.x * 64;
    __shared__ float As[16][64];
    __shared__ float Bs[16][64];
    float acc[4][4] = {};
    const int ar = tid >> 2;
    const int ak = (tid & 3) * 4;
    const int bk = tid >> 4;
    const int bn = (tid & 15) * 4;
    for (int kk = 0; kk < K; kk += 16) {
        float4 av = *(const float4*)&A[(size_t)(m0 + ar) * K + kk + ak];
        float4 bv = *(const float4*)&B[(size_t)(kk + bk) * N + n0 + bn];
        As[ak + 0][ar] = av.x; As[ak + 1][ar] = av.y;
        As[ak + 2][ar] = av.z; As[ak + 3][ar] = av.w;
        *(float4*)&Bs[bk][bn] = bv;
        __syncthreads();
#pragma unroll
        for (int k = 0; k < 16; ++k) {
            float4 a = *(const float4*)&As[k][ty * 4];
            float4 b = *(const float4*)&Bs[k][tx * 4];
            float a4[4] = {a.x, a.y, a.z, a.w};
            float b4[4] = {b.x, b.y, b.z, b.w};
#pragma unroll
            for (int i = 0; i < 4; ++i)
#pragma unroll
                for (int j = 0; j < 4; ++j) acc[i][j] += a4[i] * b4[j];
        }
        __syncthreads();
    }
#pragma unroll
    for (int i = 0; i < 4; ++i) {
        float4 o = make_float4(acc[i][0], acc[i][1], acc[i][2], acc[i][3]);
        *(float4*)&C[(size_t)(m0 + ty * 4 + i) * N + n0 + tx * 4] = o;
    }
}

// ---------------- depthwise causal conv (D_CONV=4) + bias + SiLU ----------------
__global__ void k_conv_silu(const float* __restrict__ xz, const float* __restrict__ cw,
                            const float* __restrict__ cb, float* __restrict__ u) {
    int idx = blockIdx.x * blockDim.x + threadIdx.x;
    int c  = idx & (DINNER - 1);
    int bl = idx >> 9;
    int l  = bl & (LL - 1);
    float acc = cb[c];
#pragma unroll
    for (int k = 0; k < DCONV; ++k) {
        int t = l - (DCONV - 1) + k;
        if (t >= 0) acc += cw[c * DCONV + k] * xz[(size_t)(bl - (DCONV - 1) + k) * 2 * DINNER + c];
    }
    u[(size_t)idx] = acc * sigmoidf_(acc);
}

// ---------------- fused x_proj + delta ----------------
// block = 256 threads over 8 tokens: (m = tid>>5, jg = (tid>>3)&3, s = tid&7).
// Each thread: 12-col partial over interleaved K-slice (k = 8i+s), shfl-reduced
// over s. Low VGPR (acc[12]), u staged in LDS. grid = BL/8 = 1024 blocks.
__global__ __launch_bounds__(256) void k_xpd(const float* __restrict__ u,
                                             const float* __restrict__ w_xp,
                                             const float* __restrict__ w_dt,
                                             const float* __restrict__ b_dt,
                                             float* __restrict__ Bm,
                                             float* __restrict__ Cm,
                                             float* __restrict__ delta) {
    const int tid = threadIdx.x;
    const int bl0 = blockIdx.x * 8;
    __shared__ float us[8 * DINNER];
    __shared__ float dts[8][DTRANK];

    {   // cooperative coalesced load of 8 tokens of u (4096 floats)
        const float4* u4 = (const float4*)&u[(size_t)bl0 * DINNER];
        float4* us4 = (float4*)us;
#pragma unroll
        for (int q = 0; q < 4; ++q) us4[tid + q * 256] = u4[tid + q * 256];
    }
    __syncthreads();

    const int m  = tid >> 5;
    const int jg = (tid >> 3) & 3;
    const int s  = tid & 7;

    float acc[12] = {};
    const float* usm = &us[m * DINNER];
#pragma unroll 4
    for (int i = 0; i < 64; ++i) {
        const int k = i * 8 + s;
        const float a = usm[k];
        const float* wr = &w_xp[k * 48 + jg * 12];
        float4 w0 = *(const float4*)&wr[0];
        float4 w1 = *(const float4*)&wr[4];
        float4 w2 = *(const float4*)&wr[8];
        acc[0]  = fmaf(a, w0.x, acc[0]);  acc[1]  = fmaf(a, w0.y, acc[1]);
        acc[2]  = fmaf(a, w0.z, acc[2]);  acc[3]  = fmaf(a, w0.w, acc[3]);
        acc[4]  = fmaf(a, w1.x, acc[4]);  acc[5]  = fmaf(a, w1.y, acc[5]);
        acc[6]  = fmaf(a, w1.z, acc[6]);  acc[7]  = fmaf(a, w1.w, acc[7]);
        acc[8]  = fmaf(a, w2.x, acc[8]);  acc[9]  = fmaf(a, w2.y, acc[9]);
        acc[10] = fmaf(a, w2.z, acc[10]); acc[11] = fmaf(a, w2.w, acc[11]);
    }
#pragma unroll
    for (int off = 4; off >= 1; off >>= 1) {
#pragma unroll
        for (int j = 0; j < 12; ++j) acc[j] += __shfl_xor(acc[j], off, 8);
    }
    if (s < 6) {
        const int bl = bl0 + m;
#pragma unroll
        for (int q = 0; q < 2; ++q) {
            int j = jg * 12 + s * 2 + q;
            float v = acc[s * 2 + q];
            if (j < 16)      dts[m][j] = v;
            else if (j < 32) Bm[(size_t)bl * DSTATE + (j - 16)] = v;
            else             Cm[(size_t)bl * DSTATE + (j - 32)] = v;
        }
    }
    __syncthreads();

    // phase 2: delta = softplus(dt @ w_dt + b_dt); thread: 4 channels x 4 tokens
    const int c0 = (tid & 127) * 4;
    const int mb = (tid >> 7) * 4;
    float4 bd = *(const float4*)&b_dt[c0];
    float a0[4], a1[4], a2[4], a3[4];
#pragma unroll
    for (int t = 0; t < 4; ++t) { a0[t] = bd.x; a1[t] = bd.y; a2[t] = bd.z; a3[t] = bd.w; }
#pragma unroll
    for (int r = 0; r < DTRANK; ++r) {
        float4 w4 = *(const float4*)&w_dt[r * DINNER + c0];
#pragma unroll
        for (int t = 0; t < 4; ++t) {
            float f = dts[mb + t][r];
            a0[t] = fmaf(f, w4.x, a0[t]);
            a1[t] = fmaf(f, w4.y, a1[t]);
            a2[t] = fmaf(f, w4.z, a2[t]);
            a3[t] = fmaf(f, w4.w, a3[t]);
        }
    }
#pragma unroll
    for (int t = 0; t < 4; ++t) {
        float4 o;
        o.x = (a0[t] > 20.f) ? a0[t] : log1pf(__expf(a0[t]));
        o.y = (a1[t] > 20.f) ? a1[t] : log1pf(__expf(a1[t]));
        o.z = (a2[t] > 20.f) ? a2[t] : log1pf(__expf(a2[t]));
        o.w = (a3[t] > 20.f) ? a3[t] : log1pf(__expf(a3[t]));
        *(float4*)&delta[(size_t)(bl0 + mb + t) * DINNER + c0] = o;
    }
}

// ---------------- chunked selective scan, per-channel 16-state-in-registers ----------------
__global__ __launch_bounds__(256) void k_scan_a(const float* __restrict__ delta,
                                                const float* __restrict__ u,
                                                const float* __restrict__ Bm,
                                                const float* __restrict__ A_log,
                                                float* __restrict__ aprod,
                                                float* __restrict__ hend) {
    const int tid = threadIdx.x;
    const int bid = blockIdx.x;
    const int chalf = bid & 1;
    const int k = (bid >> 1) & (NCHUNK - 1);
    const int b = bid >> 7;
    const int c = chalf * 256 + tid;
    const int bl0 = b * LL + k * LC;

    __shared__ float Bs[LC * DSTATE];
    for (int i = tid; i < LC * DSTATE; i += 256) Bs[i] = Bm[(size_t)bl0 * DSTATE + i];
    __syncthreads();

    float Ac[DSTATE];
#pragma unroll
    for (int q = 0; q < 4; ++q) {
        float4 a = *(const float4*)&A_log[c * DSTATE + q * 4];
        Ac[q * 4 + 0] = -__expf(a.x); Ac[q * 4 + 1] = -__expf(a.y);
        Ac[q * 4 + 2] = -__expf(a.z); Ac[q * 4 + 3] = -__expf(a.w);
    }

    float h[DSTATE] = {};
    float ap[DSTATE];
#pragma unroll
    for (int n = 0; n < DSTATE; ++n) ap[n] = 1.f;

    float dlt = delta[(size_t)bl0 * DINNER + c];
    float uu  = u[(size_t)bl0 * DINNER + c];
    for (int t = 0; t < LC; ++t) {
        float dlt2 = 0.f, uu2 = 0.f;
        if (t + 1 < LC) {
            dlt2 = delta[(size_t)(bl0 + t + 1) * DINNER + c];
            uu2  = u[(size_t)(bl0 + t + 1) * DINNER + c];
        }
        const float w = dlt * uu;
        const float4* Bs4 = (const float4*)&Bs[t * DSTATE];
        float4 b0 = Bs4[0], b1 = Bs4[1], b2 = Bs4[2], b3 = Bs4[3];
        float bv[DSTATE] = {b0.x, b0.y, b0.z, b0.w, b1.x, b1.y, b1.z, b1.w,
                            b2.x, b2.y, b2.z, b2.w, b3.x, b3.y, b3.z, b3.w};
#pragma unroll
        for (int n = 0; n < DSTATE; ++n) {
            float dA = __expf(dlt * Ac[n]);
            ap[n] *= dA;
            h[n] = fmaf(dA, h[n], w * bv[n]);
        }
        dlt = dlt2; uu = uu2;
    }
    size_t base = ((size_t)(k * BB + b) * DINNER + c) * DSTATE;
#pragma unroll
    for (int q = 0; q < 4; ++q) {
        *(float4*)&aprod[base + q * 4] = make_float4(ap[q*4], ap[q*4+1], ap[q*4+2], ap[q*4+3]);
        *(float4*)&hend[base + q * 4]  = make_float4(h[q*4],  h[q*4+1],  h[q*4+2],  h[q*4+3]);
    }
}

// Pass B: serial combine across chunks (one thread per (b,c,n)).
// NOTE: hstart may alias aprod (read-before-write order below).
__global__ __launch_bounds__(256) void k_scan_b(const float* __restrict__ aprod,
                                                const float* __restrict__ hend,
                                                float* __restrict__ hstart) {
    int i = blockIdx.x * 256 + threadIdx.x;
    float h = 0.f;
#pragma unroll 4
    for (int k = 0; k < NCHUNK; ++k) {
        size_t idx = (size_t)k * NREC + i;
        float a = aprod[idx];
        float e = hend[idx];
        hstart[idx] = h;
        h = fmaf(a, h, e);
    }
}

// Pass C: re-scan chunk from hstart, emit gated output.
__global__ __launch_bounds__(256) void k_scan_c(const float* __restrict__ delta,
                                                const float* __restrict__ u,
                                                const float* __restrict__ xz,
                                                const float* __restrict__ Bm,
                                                const float* __restrict__ Cm,
                                                const float* __restrict__ A_log,
                                                const float* __restrict__ Dp,
                                                const float* __restrict__ hstart,
                                                float* __restrict__ y) {
    const int tid = threadIdx.x;
    const int bid = blockIdx.x;
    const int chalf = bid & 1;
    const int k = (bid >> 1) & (NCHUNK - 1);
    const int b = bid >> 7;
    const int c = chalf * 256 + tid;
    const int bl0 = b * LL + k * LC;

    __shared__ float Bs[LC * DSTATE];
    __shared__ float Cs[LC * DSTATE];
    for (int i = tid; i < LC * DSTATE; i += 256) {
        Bs[i] = Bm[(size_t)bl0 * DSTATE + i];
        Cs[i] = Cm[(size_t)bl0 * DSTATE + i];
    }
    __syncthreads();

    float Ac[DSTATE];
#pragma unroll
    for (int q = 0; q < 4; ++q) {
        float4 a = *(const float4*)&A_log[c * DSTATE + q * 4];
        Ac[q * 4 + 0] = -__expf(a.x); Ac[q * 4 + 1] = -__expf(a.y);
        Ac[q * 4 + 2] = -__expf(a.z); Ac[q * 4 + 3] = -__expf(a.w);
    }
    const float Dc = Dp[c];

    float h[DSTATE];
    size_t hbase = ((size_t)(k * BB + b) * DINNER + c) * DSTATE;
#pragma unroll
    for (int q = 0; q < 4; ++q) {
        float4 hv = *(const float4*)&hstart[hbase + q * 4];
        h[q*4] = hv.x; h[q*4+1] = hv.y; h[q*4+2] = hv.z; h[q*4+3] = hv.w;
    }

    float dlt = delta[(size_t)bl0 * DINNER + c];
    float uu  = u[(size_t)bl0 * DINNER + c];
    float rr  = xz[(size_t)bl0 * 2 * DINNER + DINNER + c];
    for (int t = 0; t < LC; ++t) {
        float dlt2 = 0.f, uu2 = 0.f, rr2 = 0.f;
        if (t + 1 < LC) {
            dlt2 = delta[(size_t)(bl0 + t + 1) * DINNER + c];
            uu2  = u[(size_t)(bl0 + t + 1) * DINNER + c];
            rr2  = xz[(size_t)(bl0 + t + 1) * 2 * DINNER + DINNER + c];
        }
        const float w = dlt * uu;
        const float4* Bs4 = (const float4*)&Bs[t * DSTATE];
        float4 b0 = Bs4[0], b1 = Bs4[1], b2 = Bs4[2], b3 = Bs4[3];
        float bv[DSTATE] = {b0.x, b0.y, b0.z, b0.w, b1.x, b1.y, b1.z, b1.w,
                            b2.x, b2.y, b2.z, b2.w, b3.x, b3.y, b3.z, b3.w};
        const float4* Cs4 = (const float4*)&Cs[t * DSTATE];
        float4 c0 = Cs4[0], c1 = Cs4[1], c2 = Cs4[2], c3 = Cs4[3];
        float cv[DSTATE] = {c0.x, c0.y, c0.z, c0.w, c1.x, c1.y, c1.z, c1.w,
                            c2.x, c2.y, c2.z, c2.w, c3.x, c3.y, c3.z, c3.w};
        float s0 = 0.f, s1 = 0.f, s2 = 0.f, s3 = 0.f;
#pragma unroll
        for (int n = 0; n < DSTATE; n += 4) {
            float dA0 = __expf(dlt * Ac[n+0]);
            float dA1 = __expf(dlt * Ac[n+1]);
            float dA2 = __expf(dlt * Ac[n+2]);
            float dA3 = __expf(dlt * Ac[n+3]);
            h[n+0] = fmaf(dA0, h[n+0], w * bv[n+0]);
            h[n+1] = fmaf(dA1, h[n+1], w * bv[n+1]);
            h[n+2] = fmaf(dA2, h[n+2], w * bv[n+2]);
            h[n+3] = fmaf(dA3, h[n+3], w * bv[n+3]);
            s0 = fmaf(h[n+0], cv[n+0], s0);
            s1 = fmaf(h[n+1], cv[n+1], s1);
            s2 = fmaf(h[n+2], cv[n+2], s2);
            s3 = fmaf(h[n+3], cv[n+3], s3);
        }
        float yv = (s0 + s1) + (s2 + s3) + uu * Dc;
        y[(size_t)(bl0 + t) * DINNER + c] = yv * (rr * sigmoidf_(rr));
        dlt = dlt2; uu = uu2; rr = rr2;
    }
}

extern "C" void kernel_launch(void* const* d_in, const int* in_sizes, int n_in,
                              void* d_out, int out_size, void* d_ws, size_t ws_size,
                              hipStream_t stream) {
    const int*   ids   = (const int*)d_in[0];
    const float* emb   = (const float*)d_in[1];
    const float* w_in  = (const float*)d_in[2];
    const float* cw    = (const float*)d_in[3];
    const float* cb    = (const float*)d_in[4];
    const float* w_xp  = (const float*)d_in[5];
    const float* w_dt  = (const float*)d_in[6];
    const float* b_dt  = (const float*)d_in[7];
    const float* A_log = (const float*)d_in[8];
    const float* Dp    = (const float*)d_in[9];
    const float* w_out = (const float*)d_in[10];
    float* out = (float*)d_out;

    float* ws = (float*)d_ws;
    float* x   = ws;                              // BL*256 = 2.097M floats
    float* xz  = x  + (size_t)BL * DMODEL;        // BL*1024
    float* u   = xz + (size_t)BL * 2 * DINNER;    // BL*512
    float* Bm  = u  + (size_t)BL * DINNER;        // BL*16
    float* Cm  = Bm + (size_t)BL * DSTATE;        // BL*16
    float* dlt = Cm + (size_t)BL * DSTATE;        // BL*512
    float* y   = dlt + (size_t)BL * DINNER;       // BL*512
    float* hend = y + (size_t)BL * DINNER;        // NCHUNK*NREC = 2.097M
    // aprod overlays x (dead during scan); hstart aliases aprod (scan_b is
    // read-before-write per element).  NCHUNK*NREC == BL*DMODEL exactly.
    float* aprod  = x;
    float* hstart = aprod;

    k_embed<<<BL, DMODEL, 0, stream>>>(ids, emb, x);

    for (int l = 0; l < NLAYER; ++l) {
        dim3 g1(2 * DINNER / 64, BL / 64);
        k_sgemm<<<g1, 256, 0, stream>>>(x, w_in + (size_t)l * DMODEL * 2 * DINNER, xz,
                                        BL, 2 * DINNER, DMODEL);
        k_conv_silu<<<(BL * DINNER) / 256, 256, 0, stream>>>(
            xz, cw + l * DINNER * DCONV, cb + l * DINNER, u);
        k_xpd<<<BL / 8, 256, 0, stream>>>(u, w_xp + (size_t)l * DINNER * 48,
                                          w_dt + (size_t)l * DTRANK * DINNER,
                                          b_dt + (size_t)l * DINNER, Bm, Cm, dlt);
        const float* Al = A_log + (size_t)l * DINNER * DSTATE;
        k_scan_a<<<BB * NCHUNK * 2, 256, 0, stream>>>(dlt, u, Bm, Al, aprod, hend);
        k_scan_b<<<NREC / 256, 256, 0, stream>>>(aprod, hend, hstart);
        k_scan_c<<<BB * NCHUNK * 2, 256, 0, stream>>>(dlt, u, xz, Bm, Cm, Al,
                                                      Dp + (size_t)l * DINNER, hstart, y);
        float* dst = (l == NLAYER - 1) ? out : x;
        dim3 g2(DMODEL / 64, BL / 64);
        k_sgemm<<<g2, 256, 0, stream>>>(y, w_out + (size_t)l * DINNER * DMODEL, dst,
                                        BL, DMODEL, DINNER);
    }
}

// Round 6
// 475.138 us; speedup vs baseline: 1.2814x; 1.0047x over previous
//
#include <hip/hip_runtime.h>
#include <math.h>

#define NLAYER 2
#define DMODEL 256
#define DINNER 512
#define DSTATE 16
#define DTRANK 16
#define DCONV  4
#define BB     4
#define LL     2048
#define BL     (BB*LL)
#define NCHUNK 64
#define LC     (LL/NCHUNK)          // 32
#define NREC   (BB*DINNER*DSTATE)   // 32768

__device__ __forceinline__ float sigmoidf_(float x) { return 1.0f / (1.0f + __expf(-x)); }

// ---------------- fp32 tiled GEMM: C[M,N] = A[M,K] @ B[K,N] ----------------
// BM=128 fixed, BK=16, 256 threads, 8 x (NG*4) per thread.
// EMB: A row r is emb[ids[r]] (K must be 256).
// SPLITK>1: C gets SPLITK slabs of M*N (blockIdx.z picks K-slice).
template<int BN, int SPLITK, bool EMB>
__global__ __launch_bounds__(256) void k_gemm(const float* __restrict__ A,
                                              const float* __restrict__ B,
                                              float* __restrict__ C,
                                              int M, int N, int K,
                                              const int* __restrict__ ids,
                                              const float* __restrict__ emb) {
    constexpr int NG = BN / 64;
    const int tid = threadIdx.x;
    const int tx = tid & 15, ty = tid >> 4;
    const int m0 = blockIdx.y * 128, n0 = blockIdx.x * BN;
    const int Ks = K / SPLITK;
    const int k0 = blockIdx.z * Ks;
    const int KT = Ks / 16;

    __shared__ float As[16][132];   // k-major, +4 pad (2-way conflicts only)
    __shared__ float Bs[16][BN];

    const int sar = tid >> 2;          // 0..63 : row within half-tile
    const int sak = (tid & 3) * 4;     // 0,4,8,12 : k offset
    const int sbr = tid >> 4;          // 0..15 : k row
    const int sbc = (tid & 15) * 4;    // col offset

    const float* arow0;
    const float* arow1;
    if constexpr (EMB) {
        arow0 = &emb[(size_t)ids[m0 + sar] * DMODEL];
        arow1 = &emb[(size_t)ids[m0 + 64 + sar] * DMODEL];
    } else {
        arow0 = &A[(size_t)(m0 + sar) * K];
        arow1 = &A[(size_t)(m0 + 64 + sar) * K];
    }

    float4 ga0, ga1, gb[NG];
    ga0 = *(const float4*)&arow0[k0 + sak];
    ga1 = *(const float4*)&arow1[k0 + sak];
#pragma unroll
    for (int g = 0; g < NG; ++g)
        gb[g] = *(const float4*)&B[(size_t)(k0 + sbr) * N + n0 + sbc + g * 64];

    float acc[8][NG * 4] = {};

    for (int kt = 0; kt < KT; ++kt) {
        As[sak + 0][sar] = ga0.x; As[sak + 1][sar] = ga0.y;
        As[sak + 2][sar] = ga0.z; As[sak + 3][sar] = ga0.w;
        As[sak + 0][64 + sar] = ga1.x; As[sak + 1][64 + sar] = ga1.y;
        As[sak + 2][64 + sar] = ga1.z; As[sak + 3][64 + sar] = ga1.w;
#pragma unroll
        for (int g = 0; g < NG; ++g) *(float4*)&Bs[sbr][sbc + g * 64] = gb[g];
        __syncthreads();
        if (kt + 1 < KT) {
            const int kk = k0 + (kt + 1) * 16;
            ga0 = *(const float4*)&arow0[kk + sak];
            ga1 = *(const float4*)&arow1[kk + sak];
#pragma unroll
            for (int g = 0; g < NG; ++g)
                gb[g] = *(const float4*)&B[(size_t)(kk + sbr) * N + n0 + sbc + g * 64];
        }
#pragma unroll
        for (int k = 0; k < 16; ++k) {
            float4 a0 = *(const float4*)&As[k][ty * 4];
            float4 a1 = *(const float4*)&As[k][64 + ty * 4];
            float av[8] = {a0.x, a0.y, a0.z, a0.w, a1.x, a1.y, a1.z, a1.w};
            float bv[NG * 4];
            float4 b0 = *(const float4*)&Bs[k][tx * 4];
            bv[0] = b0.x; bv[1] = b0.y; bv[2] = b0.z; bv[3] = b0.w;
            if constexpr (NG == 2) {
                float4 b1 = *(const float4*)&Bs[k][64 + tx * 4];
                bv[4] = b1.x; bv[5] = b1.y; bv[6] = b1.z; bv[7] = b1.w;
            }
#pragma unroll
            for (int i = 0; i < 8; ++i)
#pragma unroll
                for (int j = 0; j < NG * 4; ++j)
                    acc[i][j] = fmaf(av[i], bv[j], acc[i][j]);
        }
        __syncthreads();
    }

    float* Cw = C + (size_t)blockIdx.z * ((size_t)M * N);
#pragma unroll
    for (int ih = 0; ih < 2; ++ih)
#pragma unroll
        for (int i = 0; i < 4; ++i) {
            const int row = m0 + ih * 64 + ty * 4 + i;
#pragma unroll
            for (int g = 0; g < NG; ++g) {
                float4 o = make_float4(acc[ih * 4 + i][g * 4 + 0], acc[ih * 4 + i][g * 4 + 1],
                                       acc[ih * 4 + i][g * 4 + 2], acc[ih * 4 + i][g * 4 + 3]);
                *(float4*)&Cw[(size_t)row * N + n0 + g * 64 + tx * 4] = o;
            }
        }
}

// sum two M*N slabs (float4)
__global__ __launch_bounds__(256) void k_red2(const float* __restrict__ p,
                                              float* __restrict__ o, int n4) {
    int i = blockIdx.x * 256 + threadIdx.x;
    const float4 a = ((const float4*)p)[i];
    const float4 b = ((const float4*)p)[i + n4];
    float4 r = make_float4(a.x + b.x, a.y + b.y, a.z + b.z, a.w + b.w);
    ((float4*)o)[i] = r;
}

// ---------------- depthwise causal conv (D_CONV=4) + bias + SiLU ----------------
__global__ void k_conv_silu(const float* __restrict__ xz, const float* __restrict__ cw,
                            const float* __restrict__ cb, float* __restrict__ u) {
    int idx = blockIdx.x * blockDim.x + threadIdx.x;
    int c  = idx & (DINNER - 1);
    int bl = idx >> 9;
    int l  = bl & (LL - 1);
    float acc = cb[c];
#pragma unroll
    for (int k = 0; k < DCONV; ++k) {
        int t = l - (DCONV - 1) + k;
        if (t >= 0) acc += cw[c * DCONV + k] * xz[(size_t)(bl - (DCONV - 1) + k) * 2 * DINNER + c];
    }
    u[(size_t)idx] = acc * sigmoidf_(acc);
}

// ---------------- fused x_proj + delta ----------------
__global__ __launch_bounds__(256) void k_xpd(const float* __restrict__ u,
                                             const float* __restrict__ w_xp,
                                             const float* __restrict__ w_dt,
                                             const float* __restrict__ b_dt,
                                             float* __restrict__ Bm,
                                             float* __restrict__ Cm,
                                             float* __restrict__ delta) {
    const int tid = threadIdx.x;
    const int bl0 = blockIdx.x * 8;
    __shared__ float us[8 * DINNER];
    __shared__ float dts[8][DTRANK];

    {
        const float4* u4 = (const float4*)&u[(size_t)bl0 * DINNER];
        float4* us4 = (float4*)us;
#pragma unroll
        for (int q = 0; q < 4; ++q) us4[tid + q * 256] = u4[tid + q * 256];
    }
    __syncthreads();

    const int m  = tid >> 5;
    const int jg = (tid >> 3) & 3;
    const int s  = tid & 7;

    float acc[12] = {};
    const float* usm = &us[m * DINNER];
#pragma unroll 4
    for (int i = 0; i < 64; ++i) {
        const int k = i * 8 + s;
        const float a = usm[k];
        const float* wr = &w_xp[k * 48 + jg * 12];
        float4 w0 = *(const float4*)&wr[0];
        float4 w1 = *(const float4*)&wr[4];
        float4 w2 = *(const float4*)&wr[8];
        acc[0]  = fmaf(a, w0.x, acc[0]);  acc[1]  = fmaf(a, w0.y, acc[1]);
        acc[2]  = fmaf(a, w0.z, acc[2]);  acc[3]  = fmaf(a, w0.w, acc[3]);
        acc[4]  = fmaf(a, w1.x, acc[4]);  acc[5]  = fmaf(a, w1.y, acc[5]);
        acc[6]  = fmaf(a, w1.z, acc[6]);  acc[7]  = fmaf(a, w1.w, acc[7]);
        acc[8]  = fmaf(a, w2.x, acc[8]);  acc[9]  = fmaf(a, w2.y, acc[9]);
        acc[10] = fmaf(a, w2.z, acc[10]); acc[11] = fmaf(a, w2.w, acc[11]);
    }
#pragma unroll
    for (int off = 4; off >= 1; off >>= 1) {
#pragma unroll
        for (int j = 0; j < 12; ++j) acc[j] += __shfl_xor(acc[j], off, 8);
    }
    if (s < 6) {
        const int bl = bl0 + m;
#pragma unroll
        for (int q = 0; q < 2; ++q) {
            int j = jg * 12 + s * 2 + q;
            float v = acc[s * 2 + q];
            if (j < 16)      dts[m][j] = v;
            else if (j < 32) Bm[(size_t)bl * DSTATE + (j - 16)] = v;
            else             Cm[(size_t)bl * DSTATE + (j - 32)] = v;
        }
    }
    __syncthreads();

    const int c0 = (tid & 127) * 4;
    const int mb = (tid >> 7) * 4;
    float4 bd = *(const float4*)&b_dt[c0];
    float a0[4], a1[4], a2[4], a3[4];
#pragma unroll
    for (int t = 0; t < 4; ++t) { a0[t] = bd.x; a1[t] = bd.y; a2[t] = bd.z; a3[t] = bd.w; }
#pragma unroll
    for (int r = 0; r < DTRANK; ++r) {
        float4 w4 = *(const float4*)&w_dt[r * DINNER + c0];
#pragma unroll
        for (int t = 0; t < 4; ++t) {
            float f = dts[mb + t][r];
            a0[t] = fmaf(f, w4.x, a0[t]);
            a1[t] = fmaf(f, w4.y, a1[t]);
            a2[t] = fmaf(f, w4.z, a2[t]);
            a3[t] = fmaf(f, w4.w, a3[t]);
        }
    }
#pragma unroll
    for (int t = 0; t < 4; ++t) {
        float4 o;
        o.x = (a0[t] > 20.f) ? a0[t] : log1pf(__expf(a0[t]));
        o.y = (a1[t] > 20.f) ? a1[t] : log1pf(__expf(a1[t]));
        o.z = (a2[t] > 20.f) ? a2[t] : log1pf(__expf(a2[t]));
        o.w = (a3[t] > 20.f) ? a3[t] : log1pf(__expf(a3[t]));
        *(float4*)&delta[(size_t)(bl0 + mb + t) * DINNER + c0] = o;
    }
}

// ---------------- chunked selective scan, per-channel 16-state-in-registers ----------------
__global__ __launch_bounds__(256) void k_scan_a(const float* __restrict__ delta,
                                                const float* __restrict__ u,
                                                const float* __restrict__ Bm,
                                                const float* __restrict__ A_log,
                                                float* __restrict__ aprod,
                                                float* __restrict__ hend) {
    const int tid = threadIdx.x;
    const int bid = blockIdx.x;
    const int chalf = bid & 1;
    const int k = (bid >> 1) & (NCHUNK - 1);
    const int b = bid >> 7;
    const int c = chalf * 256 + tid;
    const int bl0 = b * LL + k * LC;

    __shared__ float Bs[LC * DSTATE];
    for (int i = tid; i < LC * DSTATE; i += 256) Bs[i] = Bm[(size_t)bl0 * DSTATE + i];
    __syncthreads();

    float Ac[DSTATE];
#pragma unroll
    for (int q = 0; q < 4; ++q) {
        float4 a = *(const float4*)&A_log[c * DSTATE + q * 4];
        Ac[q * 4 + 0] = -__expf(a.x); Ac[q * 4 + 1] = -__expf(a.y);
        Ac[q * 4 + 2] = -__expf(a.z); Ac[q * 4 + 3] = -__expf(a.w);
    }

    float h[DSTATE] = {};
    float ap[DSTATE];
#pragma unroll
    for (int n = 0; n < DSTATE; ++n) ap[n] = 1.f;

    float dlt = delta[(size_t)bl0 * DINNER + c];
    float uu  = u[(size_t)bl0 * DINNER + c];
    for (int t = 0; t < LC; ++t) {
        float dlt2 = 0.f, uu2 = 0.f;
        if (t + 1 < LC) {
            dlt2 = delta[(size_t)(bl0 + t + 1) * DINNER + c];
            uu2  = u[(size_t)(bl0 + t + 1) * DINNER + c];
        }
        const float w = dlt * uu;
        const float4* Bs4 = (const float4*)&Bs[t * DSTATE];
        float4 b0 = Bs4[0], b1 = Bs4[1], b2 = Bs4[2], b3 = Bs4[3];
        float bv[DSTATE] = {b0.x, b0.y, b0.z, b0.w, b1.x, b1.y, b1.z, b1.w,
                            b2.x, b2.y, b2.z, b2.w, b3.x, b3.y, b3.z, b3.w};
#pragma unroll
        for (int n = 0; n < DSTATE; ++n) {
            float dA = __expf(dlt * Ac[n]);
            ap[n] *= dA;
            h[n] = fmaf(dA, h[n], w * bv[n]);
        }
        dlt = dlt2; uu = uu2;
    }
    size_t base = ((size_t)(k * BB + b) * DINNER + c) * DSTATE;
#pragma unroll
    for (int q = 0; q < 4; ++q) {
        *(float4*)&aprod[base + q * 4] = make_float4(ap[q*4], ap[q*4+1], ap[q*4+2], ap[q*4+3]);
        *(float4*)&hend[base + q * 4]  = make_float4(h[q*4],  h[q*4+1],  h[q*4+2],  h[q*4+3]);
    }
}

__global__ __launch_bounds__(256) void k_scan_b(const float* __restrict__ aprod,
                                                const float* __restrict__ hend,
                                                float* __restrict__ hstart) {
    int i = blockIdx.x * 256 + threadIdx.x;
    float h = 0.f;
#pragma unroll 4
    for (int k = 0; k < NCHUNK; ++k) {
        size_t idx = (size_t)k * NREC + i;
        float a = aprod[idx];
        float e = hend[idx];
        hstart[idx] = h;
        h = fmaf(a, h, e);
    }
}

__global__ __launch_bounds__(256) void k_scan_c(const float* __restrict__ delta,
                                                const float* __restrict__ u,
                                                const float* __restrict__ xz,
                                                const float* __restrict__ Bm,
                                                const float* __restrict__ Cm,
                                                const float* __restrict__ A_log,
                                                const float* __restrict__ Dp,
                                                const float* __restrict__ hstart,
                                                float* __restrict__ y) {
    const int tid = threadIdx.x;
    const int bid = blockIdx.x;
    const int chalf = bid & 1;
    const int k = (bid >> 1) & (NCHUNK - 1);
    const int b = bid >> 7;
    const int c = chalf * 256 + tid;
    const int bl0 = b * LL + k * LC;

    __shared__ float Bs[LC * DSTATE];
    __shared__ float Cs[LC * DSTATE];
    for (int i = tid; i < LC * DSTATE; i += 256) {
        Bs[i] = Bm[(size_t)bl0 * DSTATE + i];
        Cs[i] = Cm[(size_t)bl0 * DSTATE + i];
    }
    __syncthreads();

    float Ac[DSTATE];
#pragma unroll
    for (int q = 0; q < 4; ++q) {
        float4 a = *(const float4*)&A_log[c * DSTATE + q * 4];
        Ac[q * 4 + 0] = -__expf(a.x); Ac[q * 4 + 1] = -__expf(a.y);
        Ac[q * 4 + 2] = -__expf(a.z); Ac[q * 4 + 3] = -__expf(a.w);
    }
    const float Dc = Dp[c];

    float h[DSTATE];
    size_t hbase = ((size_t)(k * BB + b) * DINNER + c) * DSTATE;
#pragma unroll
    for (int q = 0; q < 4; ++q) {
        float4 hv = *(const float4*)&hstart[hbase + q * 4];
        h[q*4] = hv.x; h[q*4+1] = hv.y; h[q*4+2] = hv.z; h[q*4+3] = hv.w;
    }

    float dlt = delta[(size_t)bl0 * DINNER + c];
    float uu  = u[(size_t)bl0 * DINNER + c];
    float rr  = xz[(size_t)bl0 * 2 * DINNER + DINNER + c];
    for (int t = 0; t < LC; ++t) {
        float dlt2 = 0.f, uu2 = 0.f, rr2 = 0.f;
        if (t + 1 < LC) {
            dlt2 = delta[(size_t)(bl0 + t + 1) * DINNER + c];
            uu2  = u[(size_t)(bl0 + t + 1) * DINNER + c];
            rr2  = xz[(size_t)(bl0 + t + 1) * 2 * DINNER + DINNER + c];
        }
        const float w = dlt * uu;
        const float4* Bs4 = (const float4*)&Bs[t * DSTATE];
        float4 b0 = Bs4[0], b1 = Bs4[1], b2 = Bs4[2], b3 = Bs4[3];
        float bv[DSTATE] = {b0.x, b0.y, b0.z, b0.w, b1.x, b1.y, b1.z, b1.w,
                            b2.x, b2.y, b2.z, b2.w, b3.x, b3.y, b3.z, b3.w};
        const float4* Cs4 = (const float4*)&Cs[t * DSTATE];
        float4 c0 = Cs4[0], c1 = Cs4[1], c2 = Cs4[2], c3 = Cs4[3];
        float cv[DSTATE] = {c0.x, c0.y, c0.z, c0.w, c1.x, c1.y, c1.z, c1.w,
                            c2.x, c2.y, c2.z, c2.w, c3.x, c3.y, c3.z, c3.w};
        float s0 = 0.f, s1 = 0.f, s2 = 0.f, s3 = 0.f;
#pragma unroll
        for (int n = 0; n < DSTATE; n += 4) {
            float dA0 = __expf(dlt * Ac[n+0]);
            float dA1 = __expf(dlt * Ac[n+1]);
            float dA2 = __expf(dlt * Ac[n+2]);
            float dA3 = __expf(dlt * Ac[n+3]);
            h[n+0] = fmaf(dA0, h[n+0], w * bv[n+0]);
            h[n+1] = fmaf(dA1, h[n+1], w * bv[n+1]);
            h[n+2] = fmaf(dA2, h[n+2], w * bv[n+2]);
            h[n+3] = fmaf(dA3, h[n+3], w * bv[n+3]);
            s0 = fmaf(h[n+0], cv[n+0], s0);
            s1 = fmaf(h[n+1], cv[n+1], s1);
            s2 = fmaf(h[n+2], cv[n+2], s2);
            s3 = fmaf(h[n+3], cv[n+3], s3);
        }
        float yv = (s0 + s1) + (s2 + s3) + uu * Dc;
        y[(size_t)(bl0 + t) * DINNER + c] = yv * (rr * sigmoidf_(rr));
        dlt = dlt2; uu = uu2; rr = rr2;
    }
}

extern "C" void kernel_launch(void* const* d_in, const int* in_sizes, int n_in,
                              void* d_out, int out_size, void* d_ws, size_t ws_size,
                              hipStream_t stream) {
    const int*   ids   = (const int*)d_in[0];
    const float* emb   = (const float*)d_in[1];
    const float* w_in  = (const float*)d_in[2];
    const float* cw    = (const float*)d_in[3];
    const float* cb    = (const float*)d_in[4];
    const float* w_xp  = (const float*)d_in[5];
    const float* w_dt  = (const float*)d_in[6];
    const float* b_dt  = (const float*)d_in[7];
    const float* A_log = (const float*)d_in[8];
    const float* Dp    = (const float*)d_in[9];
    const float* w_out = (const float*)d_in[10];
    float* out = (float*)d_out;

    float* ws = (float*)d_ws;
    float* x   = ws;                              // BL*256 = 2.097M floats
    float* xz  = x  + (size_t)BL * DMODEL;        // BL*1024
    float* u   = xz + (size_t)BL * 2 * DINNER;    // BL*512
    float* Bm  = u  + (size_t)BL * DINNER;        // BL*16
    float* Cm  = Bm + (size_t)BL * DSTATE;        // BL*16
    float* dlt = Cm + (size_t)BL * DSTATE;        // BL*512 (also split-K partials)
    float* y   = dlt + (size_t)BL * DINNER;       // BL*512
    float* hend = y + (size_t)BL * DINNER;        // NCHUNK*NREC = 2.097M
    float* aprod  = x;     // overlays x (dead during scan)
    float* hstart = aprod; // scan_b is read-before-write per element

    for (int l = 0; l < NLAYER; ++l) {
        // in_proj: xz = A @ w_in  (A = emb-gather for l==0, else x)
        dim3 g1(2 * DINNER / 128, BL / 128, 1);
        if (l == 0)
            k_gemm<128, 1, true><<<g1, 256, 0, stream>>>(x, w_in, xz,
                BL, 2 * DINNER, DMODEL, ids, emb);
        else
            k_gemm<128, 1, false><<<g1, 256, 0, stream>>>(x, w_in + (size_t)l * DMODEL * 2 * DINNER,
                xz, BL, 2 * DINNER, DMODEL, ids, emb);

        k_conv_silu<<<(BL * DINNER) / 256, 256, 0, stream>>>(
            xz, cw + l * DINNER * DCONV, cb + l * DINNER, u);
        k_xpd<<<BL / 8, 256, 0, stream>>>(u, w_xp + (size_t)l * DINNER * 48,
                                          w_dt + (size_t)l * DTRANK * DINNER,
                                          b_dt + (size_t)l * DINNER, Bm, Cm, dlt);
        const float* Al = A_log + (size_t)l * DINNER * DSTATE;
        k_scan_a<<<BB * NCHUNK * 2, 256, 0, stream>>>(dlt, u, Bm, Al, aprod, hend);
        k_scan_b<<<NREC / 256, 256, 0, stream>>>(aprod, hend, hstart);
        k_scan_c<<<BB * NCHUNK * 2, 256, 0, stream>>>(dlt, u, xz, Bm, Cm, Al,
                                                      Dp + (size_t)l * DINNER, hstart, y);

        // out_proj: split-K=2 partials into dlt (dead now), then reduce into dst
        float* dst = (l == NLAYER - 1) ? out : x;
        dim3 g2(DMODEL / 64, BL / 128, 2);
        k_gemm<64, 2, false><<<g2, 256, 0, stream>>>(y, w_out + (size_t)l * DINNER * DMODEL,
                                                     dlt, BL, DMODEL, DINNER, ids, emb);
        k_red2<<<(BL * DMODEL / 4) / 256, 256, 0, stream>>>(dlt, dst, BL * DMODEL / 4);
    }
}

// Round 7
// 390.599 us; speedup vs baseline: 1.5588x; 1.2164x over previous
//
#include <hip/hip_runtime.h>
#include <math.h>

#define NLAYER 2
#define DMODEL 256
#define DINNER 512
#define DSTATE 16
#define DTRANK 16
#define DCONV  4
#define BB     4
#define LL     2048
#define BL     (BB*LL)
#define NCHUNK 64
#define LC     (LL/NCHUNK)          // 32
#define NREC   (BB*DINNER*DSTATE)   // 32768

typedef __attribute__((ext_vector_type(8))) short short8;   // 8 bf16 (4 VGPRs)
typedef __attribute__((ext_vector_type(4))) float f32x4;    // 4 fp32 acc

__device__ __forceinline__ float sigmoidf_(float x) { return 1.0f / (1.0f + __expf(-x)); }

// fp32 -> bf16 round-to-nearest-even (bit pattern) and back
__device__ __forceinline__ unsigned f2bf(float a) {
    unsigned u = __builtin_bit_cast(unsigned, a);
    return (u + 0x7fffu + ((u >> 16) & 1u)) >> 16;
}
__device__ __forceinline__ float bf2f(unsigned h) {
    return __builtin_bit_cast(float, h << 16);
}

// ---------------- activation fp32 [M,K] (or emb-gather) -> frag bf16 hi/lo ----------------
// frag layout: [M/16][2K/32][64 lanes][8]; lane l holds A[mf*16+(l&15)][kf*32+(l>>4)*8+j]
// hi part at kf in [0,K/32), lo part at kf + K/32.
template<int K, bool EMB>
__global__ __launch_bounds__(256) void k_cvt_a(const float* __restrict__ A,
                                               ushort* __restrict__ F,
                                               const int* __restrict__ ids,
                                               const float* __restrict__ emb) {
    constexpr int NKF = K / 32;
    const int t = blockIdx.x * 256 + threadIdx.x;
    const int l = t & 63;
    const int cid = t >> 6;
    const int kf = cid % NKF;
    const int mf = cid / NKF;
    const int row = mf * 16 + (l & 15);
    const int k0 = kf * 32 + (l >> 4) * 8;
    const float* src = EMB ? &emb[(size_t)ids[row] * K + k0]
                           : &A[(size_t)row * K + k0];
    float4 v0 = *(const float4*)&src[0];
    float4 v1 = *(const float4*)&src[4];
    float s[8] = {v0.x, v0.y, v0.z, v0.w, v1.x, v1.y, v1.z, v1.w};
    unsigned hi[8], lo[8];
#pragma unroll
    for (int j = 0; j < 8; ++j) {
        hi[j] = f2bf(s[j]);
        lo[j] = f2bf(s[j] - bf2f(hi[j]));
    }
    uint4 ph = make_uint4(hi[0] | (hi[1] << 16), hi[2] | (hi[3] << 16),
                          hi[4] | (hi[5] << 16), hi[6] | (hi[7] << 16));
    uint4 pl = make_uint4(lo[0] | (lo[1] << 16), lo[2] | (lo[3] << 16),
                          lo[4] | (lo[5] << 16), lo[6] | (lo[7] << 16));
    size_t ohi = ((size_t)mf * (2 * NKF) + kf) * 512 + l * 8;
    *(uint4*)&F[ohi] = ph;
    *(uint4*)&F[ohi + (size_t)NKF * 512] = pl;
}

// ---------------- weight fp32 [K,N] -> frag bf16 hi/lo ----------------
// frag layout: [N/16][2K/32][64][8]; lane l holds B[kf*32+(l>>4)*8+j][nf*16+(l&15)]
template<int K>
__global__ __launch_bounds__(256) void k_cvt_w(const float* __restrict__ W,
                                               ushort* __restrict__ F, int N) {
    constexpr int NKF = K / 32;
    const int t = blockIdx.x * 256 + threadIdx.x;
    const int l = t & 63;
    const int cid = t >> 6;
    const int kf = cid % NKF;
    const int nf = cid / NKF;
    const int col = nf * 16 + (l & 15);
    const int k0 = kf * 32 + (l >> 4) * 8;
    float s[8];
#pragma unroll
    for (int j = 0; j < 8; ++j) s[j] = W[(size_t)(k0 + j) * N + col];
    unsigned hi[8], lo[8];
#pragma unroll
    for (int j = 0; j < 8; ++j) {
        hi[j] = f2bf(s[j]);
        lo[j] = f2bf(s[j] - bf2f(hi[j]));
    }
    uint4 ph = make_uint4(hi[0] | (hi[1] << 16), hi[2] | (hi[3] << 16),
                          hi[4] | (hi[5] << 16), hi[6] | (hi[7] << 16));
    uint4 pl = make_uint4(lo[0] | (lo[1] << 16), lo[2] | (lo[3] << 16),
                          lo[4] | (lo[5] << 16), lo[6] | (lo[7] << 16));
    size_t ohi = ((size_t)nf * (2 * NKF) + kf) * 512 + l * 8;
    *(uint4*)&F[ohi] = ph;
    *(uint4*)&F[ohi + (size_t)NKF * 512] = pl;
}

// ---------------- bf16 MFMA GEMM on fragment-ready inputs ----------------
// C[M,N] fp32 = Af @ Bf, tile 128x128, 256 thr = 4 waves (2x2), per-wave 64x64.
// Per K-step(32): 4 global_load_lds(16B) + 8 ds_read_b128 + 16 MFMA (m97 recipe).
// SPLITK>1: blockIdx.z picks K-slice, writes slab z of C.
template<int SPLITK>
__global__ __launch_bounds__(256) void k_mgemm(const ushort* __restrict__ Af,
                                               const ushort* __restrict__ Bf,
                                               float* __restrict__ C,
                                               int M, int N, int KE) {
    __shared__ __align__(16) ushort As[8 * 512];
    __shared__ __align__(16) ushort Bs[8 * 512];
    const int tid = threadIdx.x;
    const int w = tid >> 6, lane = tid & 63;
    const int n0 = blockIdx.x * 128, m0 = blockIdx.y * 128;
    const int nkf = KE >> 5;
    const int KT = nkf / SPLITK;
    const int kt0 = blockIdx.z * KT;
    const int wm = w & 1, wn = w >> 1;
    const int c0 = 2 * w, c1 = c0 + 1;

    f32x4 acc[4][4] = {};

    const ushort* Ab0 = Af + ((size_t)(m0 / 16 + c0) * nkf) * 512 + lane * 8;
    const ushort* Ab1 = Af + ((size_t)(m0 / 16 + c1) * nkf) * 512 + lane * 8;
    const ushort* Bb0 = Bf + ((size_t)(n0 / 16 + c0) * nkf) * 512 + lane * 8;
    const ushort* Bb1 = Bf + ((size_t)(n0 / 16 + c1) * nkf) * 512 + lane * 8;
    ushort* As0 = As + c0 * 512 + lane * 8;
    ushort* As1 = As + c1 * 512 + lane * 8;
    ushort* Bs0 = Bs + c0 * 512 + lane * 8;
    ushort* Bs1 = Bs + c1 * 512 + lane * 8;

    for (int kt = kt0; kt < kt0 + KT; ++kt) {
        const size_t ko = (size_t)kt * 512;
        __builtin_amdgcn_global_load_lds((const __attribute__((address_space(1))) void*)(Ab0 + ko),
                                         (__attribute__((address_space(3))) void*)As0, 16, 0, 0);
        __builtin_amdgcn_global_load_lds((const __attribute__((address_space(1))) void*)(Ab1 + ko),
                                         (__attribute__((address_space(3))) void*)As1, 16, 0, 0);
        __builtin_amdgcn_global_load_lds((const __attribute__((address_space(1))) void*)(Bb0 + ko),
                                         (__attribute__((address_space(3))) void*)Bs0, 16, 0, 0);
        __builtin_amdgcn_global_load_lds((const __attribute__((address_space(1))) void*)(Bb1 + ko),
                                         (__attribute__((address_space(3))) void*)Bs1, 16, 0, 0);
        __syncthreads();
        short8 av[4], bv[4];
#pragma unroll
        for (int i = 0; i < 4; ++i)
            av[i] = *(const short8*)&As[(wm * 4 + i) * 512 + lane * 8];
#pragma unroll
        for (int i = 0; i < 4; ++i)
            bv[i] = *(const short8*)&Bs[(wn * 4 + i) * 512 + lane * 8];
#pragma unroll
        for (int mi = 0; mi < 4; ++mi)
#pragma unroll
            for (int ni = 0; ni < 4; ++ni)
                acc[mi][ni] = __builtin_amdgcn_mfma_f32_16x16x32_bf16(av[mi], bv[ni],
                                                                      acc[mi][ni], 0, 0, 0);
        __syncthreads();
    }

    // C/D layout (m89-verified): col = lane&15, row = (lane>>4)*4 + reg
    float* Cw = C + (size_t)blockIdx.z * ((size_t)M * N);
    const int r0 = (lane >> 4) * 4, cc = lane & 15;
#pragma unroll
    for (int mi = 0; mi < 4; ++mi)
#pragma unroll
        for (int r = 0; r < 4; ++r) {
            const int row = m0 + wm * 64 + mi * 16 + r0 + r;
            float* crow = &Cw[(size_t)row * N + n0 + wn * 64 + cc];
#pragma unroll
            for (int ni = 0; ni < 4; ++ni) crow[ni * 16] = acc[mi][ni][r];
        }
}

// sum 4 M*N slabs (float4)
__global__ __launch_bounds__(256) void k_red4(const float* __restrict__ p,
                                              float* __restrict__ o, int n4) {
    int i = blockIdx.x * 256 + threadIdx.x;
    const float4* p4 = (const float4*)p;
    float4 a = p4[i], b = p4[i + n4], c = p4[i + 2 * n4], d = p4[i + 3 * n4];
    ((float4*)o)[i] = make_float4(a.x + b.x + c.x + d.x, a.y + b.y + c.y + d.y,
                                  a.z + b.z + c.z + d.z, a.w + b.w + c.w + d.w);
}

// ---------------- depthwise causal conv (D_CONV=4) + bias + SiLU ----------------
__global__ void k_conv_silu(const float* __restrict__ xz, const float* __restrict__ cw,
                            const float* __restrict__ cb, float* __restrict__ u) {
    int idx = blockIdx.x * blockDim.x + threadIdx.x;
    int c  = idx & (DINNER - 1);
    int bl = idx >> 9;
    int l  = bl & (LL - 1);
    float acc = cb[c];
#pragma unroll
    for (int k = 0; k < DCONV; ++k) {
        int t = l - (DCONV - 1) + k;
        if (t >= 0) acc += cw[c * DCONV + k] * xz[(size_t)(bl - (DCONV - 1) + k) * 2 * DINNER + c];
    }
    u[(size_t)idx] = acc * sigmoidf_(acc);
}

// ---------------- fused x_proj + delta ----------------
__global__ __launch_bounds__(256) void k_xpd(const float* __restrict__ u,
                                             const float* __restrict__ w_xp,
                                             const float* __restrict__ w_dt,
                                             const float* __restrict__ b_dt,
                                             float* __restrict__ Bm,
                                             float* __restrict__ Cm,
                                             float* __restrict__ delta) {
    const int tid = threadIdx.x;
    const int bl0 = blockIdx.x * 8;
    __shared__ float us[8 * DINNER];
    __shared__ float dts[8][DTRANK];

    {
        const float4* u4 = (const float4*)&u[(size_t)bl0 * DINNER];
        float4* us4 = (float4*)us;
#pragma unroll
        for (int q = 0; q < 4; ++q) us4[tid + q * 256] = u4[tid + q * 256];
    }
    __syncthreads();

    const int m  = tid >> 5;
    const int jg = (tid >> 3) & 3;
    const int s  = tid & 7;

    float acc[12] = {};
    const float* usm = &us[m * DINNER];
#pragma unroll 4
    for (int i = 0; i < 64; ++i) {
        const int k = i * 8 + s;
        const float a = usm[k];
        const float* wr = &w_xp[k * 48 + jg * 12];
        float4 w0 = *(const float4*)&wr[0];
        float4 w1 = *(const float4*)&wr[4];
        float4 w2 = *(const float4*)&wr[8];
        acc[0]  = fmaf(a, w0.x, acc[0]);  acc[1]  = fmaf(a, w0.y, acc[1]);
        acc[2]  = fmaf(a, w0.z, acc[2]);  acc[3]  = fmaf(a, w0.w, acc[3]);
        acc[4]  = fmaf(a, w1.x, acc[4]);  acc[5]  = fmaf(a, w1.y, acc[5]);
        acc[6]  = fmaf(a, w1.z, acc[6]);  acc[7]  = fmaf(a, w1.w, acc[7]);
        acc[8]  = fmaf(a, w2.x, acc[8]);  acc[9]  = fmaf(a, w2.y, acc[9]);
        acc[10] = fmaf(a, w2.z, acc[10]); acc[11] = fmaf(a, w2.w, acc[11]);
    }
#pragma unroll
    for (int off = 4; off >= 1; off >>= 1) {
#pragma unroll
        for (int j = 0; j < 12; ++j) acc[j] += __shfl_xor(acc[j], off, 8);
    }
    if (s < 6) {
        const int bl = bl0 + m;
#pragma unroll
        for (int q = 0; q < 2; ++q) {
            int j = jg * 12 + s * 2 + q;
            float v = acc[s * 2 + q];
            if (j < 16)      dts[m][j] = v;
            else if (j < 32) Bm[(size_t)bl * DSTATE + (j - 16)] = v;
            else             Cm[(size_t)bl * DSTATE + (j - 32)] = v;
        }
    }
    __syncthreads();

    const int c0 = (tid & 127) * 4;
    const int mb = (tid >> 7) * 4;
    float4 bd = *(const float4*)&b_dt[c0];
    float a0[4], a1[4], a2[4], a3[4];
#pragma unroll
    for (int t = 0; t < 4; ++t) { a0[t] = bd.x; a1[t] = bd.y; a2[t] = bd.z; a3[t] = bd.w; }
#pragma unroll
    for (int r = 0; r < DTRANK; ++r) {
        float4 w4 = *(const float4*)&w_dt[r * DINNER + c0];
#pragma unroll
        for (int t = 0; t < 4; ++t) {
            float f = dts[mb + t][r];
            a0[t] = fmaf(f, w4.x, a0[t]);
            a1[t] = fmaf(f, w4.y, a1[t]);
            a2[t] = fmaf(f, w4.z, a2[t]);
            a3[t] = fmaf(f, w4.w, a3[t]);
        }
    }
#pragma unroll
    for (int t = 0; t < 4; ++t) {
        float4 o;
        o.x = (a0[t] > 20.f) ? a0[t] : log1pf(__expf(a0[t]));
        o.y = (a1[t] > 20.f) ? a1[t] : log1pf(__expf(a1[t]));
        o.z = (a2[t] > 20.f) ? a2[t] : log1pf(__expf(a2[t]));
        o.w = (a3[t] > 20.f) ? a3[t] : log1pf(__expf(a3[t]));
        *(float4*)&delta[(size_t)(bl0 + mb + t) * DINNER + c0] = o;
    }
}

// ---------------- chunked selective scan, per-channel 16-state-in-registers ----------------
__global__ __launch_bounds__(256) void k_scan_a(const float* __restrict__ delta,
                                                const float* __restrict__ u,
                                                const float* __restrict__ Bm,
                                                const float* __restrict__ A_log,
                                                float* __restrict__ aprod,
                                                float* __restrict__ hend) {
    const int tid = threadIdx.x;
    const int bid = blockIdx.x;
    const int chalf = bid & 1;
    const int k = (bid >> 1) & (NCHUNK - 1);
    const int b = bid >> 7;
    const int c = chalf * 256 + tid;
    const int bl0 = b * LL + k * LC;

    __shared__ float Bs[LC * DSTATE];
    for (int i = tid; i < LC * DSTATE; i += 256) Bs[i] = Bm[(size_t)bl0 * DSTATE + i];
    __syncthreads();

    float Ac[DSTATE];
#pragma unroll
    for (int q = 0; q < 4; ++q) {
        float4 a = *(const float4*)&A_log[c * DSTATE + q * 4];
        Ac[q * 4 + 0] = -__expf(a.x); Ac[q * 4 + 1] = -__expf(a.y);
        Ac[q * 4 + 2] = -__expf(a.z); Ac[q * 4 + 3] = -__expf(a.w);
    }

    float h[DSTATE] = {};
    float ap[DSTATE];
#pragma unroll
    for (int n = 0; n < DSTATE; ++n) ap[n] = 1.f;

    float dlt = delta[(size_t)bl0 * DINNER + c];
    float uu  = u[(size_t)bl0 * DINNER + c];
    for (int t = 0; t < LC; ++t) {
        float dlt2 = 0.f, uu2 = 0.f;
        if (t + 1 < LC) {
            dlt2 = delta[(size_t)(bl0 + t + 1) * DINNER + c];
            uu2  = u[(size_t)(bl0 + t + 1) * DINNER + c];
        }
        const float w = dlt * uu;
        const float4* Bs4 = (const float4*)&Bs[t * DSTATE];
        float4 b0 = Bs4[0], b1 = Bs4[1], b2 = Bs4[2], b3 = Bs4[3];
        float bv[DSTATE] = {b0.x, b0.y, b0.z, b0.w, b1.x, b1.y, b1.z, b1.w,
                            b2.x, b2.y, b2.z, b2.w, b3.x, b3.y, b3.z, b3.w};
#pragma unroll
        for (int n = 0; n < DSTATE; ++n) {
            float dA = __expf(dlt * Ac[n]);
            ap[n] *= dA;
            h[n] = fmaf(dA, h[n], w * bv[n]);
        }
        dlt = dlt2; uu = uu2;
    }
    size_t base = ((size_t)(k * BB + b) * DINNER + c) * DSTATE;
#pragma unroll
    for (int q = 0; q < 4; ++q) {
        *(float4*)&aprod[base + q * 4] = make_float4(ap[q*4], ap[q*4+1], ap[q*4+2], ap[q*4+3]);
        *(float4*)&hend[base + q * 4]  = make_float4(h[q*4],  h[q*4+1],  h[q*4+2],  h[q*4+3]);
    }
}

__global__ __launch_bounds__(256) void k_scan_b(const float* __restrict__ aprod,
                                                const float* __restrict__ hend,
                                                float* __restrict__ hstart) {
    int i = blockIdx.x * 256 + threadIdx.x;
    float h = 0.f;
#pragma unroll 4
    for (int k = 0; k < NCHUNK; ++k) {
        size_t idx = (size_t)k * NREC + i;
        float a = aprod[idx];
        float e = hend[idx];
        hstart[idx] = h;
        h = fmaf(a, h, e);
    }
}

__global__ __launch_bounds__(256) void k_scan_c(const float* __restrict__ delta,
                                                const float* __restrict__ u,
                                                const float* __restrict__ xz,
                                                const float* __restrict__ Bm,
                                                const float* __restrict__ Cm,
                                                const float* __restrict__ A_log,
                                                const float* __restrict__ Dp,
                                                const float* __restrict__ hstart,
                                                float* __restrict__ y) {
    const int tid = threadIdx.x;
    const int bid = blockIdx.x;
    const int chalf = bid & 1;
    const int k = (bid >> 1) & (NCHUNK - 1);
    const int b = bid >> 7;
    const int c = chalf * 256 + tid;
    const int bl0 = b * LL + k * LC;

    __shared__ float Bs[LC * DSTATE];
    __shared__ float Cs[LC * DSTATE];
    for (int i = tid; i < LC * DSTATE; i += 256) {
        Bs[i] = Bm[(size_t)bl0 * DSTATE + i];
        Cs[i] = Cm[(size_t)bl0 * DSTATE + i];
    }
    __syncthreads();

    float Ac[DSTATE];
#pragma unroll
    for (int q = 0; q < 4; ++q) {
        float4 a = *(const float4*)&A_log[c * DSTATE + q * 4];
        Ac[q * 4 + 0] = -__expf(a.x); Ac[q * 4 + 1] = -__expf(a.y);
        Ac[q * 4 + 2] = -__expf(a.z); Ac[q * 4 + 3] = -__expf(a.w);
    }
    const float Dc = Dp[c];

    float h[DSTATE];
    size_t hbase = ((size_t)(k * BB + b) * DINNER + c) * DSTATE;
#pragma unroll
    for (int q = 0; q < 4; ++q) {
        float4 hv = *(const float4*)&hstart[hbase + q * 4];
        h[q*4] = hv.x; h[q*4+1] = hv.y; h[q*4+2] = hv.z; h[q*4+3] = hv.w;
    }

    float dlt = delta[(size_t)bl0 * DINNER + c];
    float uu  = u[(size_t)bl0 * DINNER + c];
    float rr  = xz[(size_t)bl0 * 2 * DINNER + DINNER + c];
    for (int t = 0; t < LC; ++t) {
        float dlt2 = 0.f, uu2 = 0.f, rr2 = 0.f;
        if (t + 1 < LC) {
            dlt2 = delta[(size_t)(bl0 + t + 1) * DINNER + c];
            uu2  = u[(size_t)(bl0 + t + 1) * DINNER + c];
            rr2  = xz[(size_t)(bl0 + t + 1) * 2 * DINNER + DINNER + c];
        }
        const float w = dlt * uu;
        const float4* Bs4 = (const float4*)&Bs[t * DSTATE];
        float4 b0 = Bs4[0], b1 = Bs4[1], b2 = Bs4[2], b3 = Bs4[3];
        float bv[DSTATE] = {b0.x, b0.y, b0.z, b0.w, b1.x, b1.y, b1.z, b1.w,
                            b2.x, b2.y, b2.z, b2.w, b3.x, b3.y, b3.z, b3.w};
        const float4* Cs4 = (const float4*)&Cs[t * DSTATE];
        float4 c0 = Cs4[0], c1 = Cs4[1], c2 = Cs4[2], c3 = Cs4[3];
        float cv[DSTATE] = {c0.x, c0.y, c0.z, c0.w, c1.x, c1.y, c1.z, c1.w,
                            c2.x, c2.y, c2.z, c2.w, c3.x, c3.y, c3.z, c3.w};
        float s0 = 0.f, s1 = 0.f, s2 = 0.f, s3 = 0.f;
#pragma unroll
        for (int n = 0; n < DSTATE; n += 4) {
            float dA0 = __expf(dlt * Ac[n+0]);
            float dA1 = __expf(dlt * Ac[n+1]);
            float dA2 = __expf(dlt * Ac[n+2]);
            float dA3 = __expf(dlt * Ac[n+3]);
            h[n+0] = fmaf(dA0, h[n+0], w * bv[n+0]);
            h[n+1] = fmaf(dA1, h[n+1], w * bv[n+1]);
            h[n+2] = fmaf(dA2, h[n+2], w * bv[n+2]);
            h[n+3] = fmaf(dA3, h[n+3], w * bv[n+3]);
            s0 = fmaf(h[n+0], cv[n+0], s0);
            s1 = fmaf(h[n+1], cv[n+1], s1);
            s2 = fmaf(h[n+2], cv[n+2], s2);
            s3 = fmaf(h[n+3], cv[n+3], s3);
        }
        float yv = (s0 + s1) + (s2 + s3) + uu * Dc;
        y[(size_t)(bl0 + t) * DINNER + c] = yv * (rr * sigmoidf_(rr));
        dlt = dlt2; uu = uu2; rr = rr2;
    }
}

extern "C" void kernel_launch(void* const* d_in, const int* in_sizes, int n_in,
                              void* d_out, int out_size, void* d_ws, size_t ws_size,
                              hipStream_t stream) {
    const int*   ids   = (const int*)d_in[0];
    const float* emb   = (const float*)d_in[1];
    const float* w_in  = (const float*)d_in[2];
    const float* cw    = (const float*)d_in[3];
    const float* cb    = (const float*)d_in[4];
    const float* w_xp  = (const float*)d_in[5];
    const float* w_dt  = (const float*)d_in[6];
    const float* b_dt  = (const float*)d_in[7];
    const float* A_log = (const float*)d_in[8];
    const float* Dp    = (const float*)d_in[9];
    const float* w_out = (const float*)d_in[10];
    float* out = (float*)d_out;

    float* ws = (float*)d_ws;
    float* x    = ws;                              // BL*256  = 2.10M floats
    float* xz   = x  + (size_t)BL * DMODEL;        // BL*1024 = 8.39M (also split-K partials)
    float* u    = xz + (size_t)BL * 2 * DINNER;    // BL*512  = 4.19M (also y_frag bf16)
    float* Bm   = u  + (size_t)BL * DINNER;        // BL*16
    float* Cm   = Bm + (size_t)BL * DSTATE;        // BL*16
    float* dlt  = Cm + (size_t)BL * DSTATE;        // BL*512
    float* y    = dlt + (size_t)BL * DINNER;       // BL*512
    float* hend = y + (size_t)BL * DINNER;         // 2.10M (also x_frag bf16)
    float* wfif = hend + (size_t)NCHUNK * NREC;    // 262144 floats (w_in frag)
    float* wfof = wfif + 262144;                   // 131072 floats (w_out frag)
    float* aprod  = x;     // overlays x (dead during scan)
    float* hstart = aprod; // scan_b is read-before-write per element
    ushort* xfrag = (ushort*)hend;  // alive cvt->in_proj only; scan_a writes hend later
    ushort* yfrag = (ushort*)u;     // alive cvt->out_proj only; u dead after scan_c
    ushort* wfi = (ushort*)wfif;
    ushort* wfo = (ushort*)wfof;

    for (int l = 0; l < NLAYER; ++l) {
        // ---- in_proj: xz = A @ w_in via split-bf16 MFMA (A = emb-gather for l==0)
        if (l == 0)
            k_cvt_a<DMODEL, true><<<1024, 256, 0, stream>>>(x, xfrag, ids, emb);
        else
            k_cvt_a<DMODEL, false><<<1024, 256, 0, stream>>>(x, xfrag, ids, emb);
        k_cvt_w<DMODEL><<<128, 256, 0, stream>>>(w_in + (size_t)l * DMODEL * 2 * DINNER,
                                                 wfi, 2 * DINNER);
        k_mgemm<1><<<dim3(2 * DINNER / 128, BL / 128, 1), 256, 0, stream>>>(
            xfrag, wfi, xz, BL, 2 * DINNER, 2 * DMODEL);

        k_conv_silu<<<(BL * DINNER) / 256, 256, 0, stream>>>(
            xz, cw + l * DINNER * DCONV, cb + l * DINNER, u);
        k_xpd<<<BL / 8, 256, 0, stream>>>(u, w_xp + (size_t)l * DINNER * 48,
                                          w_dt + (size_t)l * DTRANK * DINNER,
                                          b_dt + (size_t)l * DINNER, Bm, Cm, dlt);
        const float* Al = A_log + (size_t)l * DINNER * DSTATE;
        k_scan_a<<<BB * NCHUNK * 2, 256, 0, stream>>>(dlt, u, Bm, Al, aprod, hend);
        k_scan_b<<<NREC / 256, 256, 0, stream>>>(aprod, hend, hstart);
        k_scan_c<<<BB * NCHUNK * 2, 256, 0, stream>>>(dlt, u, xz, Bm, Cm, Al,
                                                      Dp + (size_t)l * DINNER, hstart, y);

        // ---- out_proj: dst = y @ w_out via split-bf16 MFMA, split-K=4 into xz
        k_cvt_a<DINNER, false><<<2048, 256, 0, stream>>>(y, yfrag, ids, emb);
        k_cvt_w<DINNER><<<64, 256, 0, stream>>>(w_out + (size_t)l * DINNER * DMODEL,
                                                wfo, DMODEL);
        float* dst = (l == NLAYER - 1) ? out : x;
        k_mgemm<4><<<dim3(DMODEL / 128, BL / 128, 4), 256, 0, stream>>>(
            yfrag, wfo, xz, BL, DMODEL, 2 * DINNER);
        k_red4<<<(BL * DMODEL / 4) / 256, 256, 0, stream>>>(xz, dst, BL * DMODEL / 4);
    }
}

// Round 9
// 335.717 us; speedup vs baseline: 1.8136x; 1.1635x over previous
//
#include <hip/hip_runtime.h>
#include <math.h>

#define NLAYER 2
#define DMODEL 256
#define DINNER 512
#define DSTATE 16
#define DTRANK 16
#define DCONV  4
#define BB     4
#define LL     2048
#define BL     (BB*LL)
#define NCHUNK 64
#define LC     (LL/NCHUNK)          // 32
#define NREC   (BB*DINNER*DSTATE)   // 32768

typedef __attribute__((ext_vector_type(8))) short short8;   // 8 bf16 (4 VGPRs)
typedef __attribute__((ext_vector_type(4))) float f32x4;    // 4 fp32 acc

__device__ __forceinline__ float sigmoidf_(float x) { return 1.0f / (1.0f + __expf(-x)); }

// fp32 -> bf16 round-to-nearest-even (bit pattern) and back
__device__ __forceinline__ unsigned f2bf(float a) {
    unsigned u = __builtin_bit_cast(unsigned, a);
    return (u + 0x7fffu + ((u >> 16) & 1u)) >> 16;
}
__device__ __forceinline__ float bf2f(unsigned h) {
    return __builtin_bit_cast(float, h << 16);
}

// ---------------- activation fp32 [M,K] (or emb-gather) -> frag bf16 hi/lo ----------------
// frag layout: [M/16][2K/32][64 lanes][8]; lane l holds A[mf*16+(l&15)][kf*32+(l>>4)*8+j]
// hi part at kf in [0,K/32), lo part at kf + K/32.
template<int K, bool EMB>
__global__ __launch_bounds__(256) void k_cvt_a(const float* __restrict__ A,
                                               ushort* __restrict__ F,
                                               const int* __restrict__ ids,
                                               const float* __restrict__ emb) {
    constexpr int NKF = K / 32;
    const int t = blockIdx.x * 256 + threadIdx.x;
    const int l = t & 63;
    const int cid = t >> 6;
    const int kf = cid % NKF;
    const int mf = cid / NKF;
    const int row = mf * 16 + (l & 15);
    const int k0 = kf * 32 + (l >> 4) * 8;
    const float* src = EMB ? &emb[(size_t)ids[row] * K + k0]
                           : &A[(size_t)row * K + k0];
    float4 v0 = *(const float4*)&src[0];
    float4 v1 = *(const float4*)&src[4];
    float s[8] = {v0.x, v0.y, v0.z, v0.w, v1.x, v1.y, v1.z, v1.w};
    unsigned hi[8], lo[8];
#pragma unroll
    for (int j = 0; j < 8; ++j) {
        hi[j] = f2bf(s[j]);
        lo[j] = f2bf(s[j] - bf2f(hi[j]));
    }
    uint4 ph = make_uint4(hi[0] | (hi[1] << 16), hi[2] | (hi[3] << 16),
                          hi[4] | (hi[5] << 16), hi[6] | (hi[7] << 16));
    uint4 pl = make_uint4(lo[0] | (lo[1] << 16), lo[2] | (lo[3] << 16),
                          lo[4] | (lo[5] << 16), lo[6] | (lo[7] << 16));
    size_t ohi = ((size_t)mf * (2 * NKF) + kf) * 512 + l * 8;
    *(uint4*)&F[ohi] = ph;
    *(uint4*)&F[ohi + (size_t)NKF * 512] = pl;
}

// ---------------- weight fp32 [K,N] -> frag bf16 hi/lo ----------------
// frag layout: [N/16][2K/32][64][8]; lane l holds B[kf*32+(l>>4)*8+j][nf*16+(l&15)]
template<int K>
__global__ __launch_bounds__(256) void k_cvt_w(const float* __restrict__ W,
                                               ushort* __restrict__ F, int N) {
    constexpr int NKF = K / 32;
    const int t = blockIdx.x * 256 + threadIdx.x;
    const int l = t & 63;
    const int cid = t >> 6;
    const int kf = cid % NKF;
    const int nf = cid / NKF;
    const int col = nf * 16 + (l & 15);
    const int k0 = kf * 32 + (l >> 4) * 8;
    float s[8];
#pragma unroll
    for (int j = 0; j < 8; ++j) s[j] = W[(size_t)(k0 + j) * N + col];
    unsigned hi[8], lo[8];
#pragma unroll
    for (int j = 0; j < 8; ++j) {
        hi[j] = f2bf(s[j]);
        lo[j] = f2bf(s[j] - bf2f(hi[j]));
    }
    uint4 ph = make_uint4(hi[0] | (hi[1] << 16), hi[2] | (hi[3] << 16),
                          hi[4] | (hi[5] << 16), hi[6] | (hi[7] << 16));
    uint4 pl = make_uint4(lo[0] | (lo[1] << 16), lo[2] | (lo[3] << 16),
                          lo[4] | (lo[5] << 16), lo[6] | (lo[7] << 16));
    size_t ohi = ((size_t)nf * (2 * NKF) + kf) * 512 + l * 8;
    *(uint4*)&F[ohi] = ph;
    *(uint4*)&F[ohi + (size_t)NKF * 512] = pl;
}

// ---------------- bf16 MFMA GEMM on fragment-ready inputs ----------------
// C[M,N] fp32 = Af @ Bf, tile 128x128, 256 thr = 4 waves (2x2), per-wave 64x64.
template<int SPLITK>
__global__ __launch_bounds__(256) void k_mgemm(const ushort* __restrict__ Af,
                                               const ushort* __restrict__ Bf,
                                               float* __restrict__ C,
                                               int M, int N, int KE) {
    __shared__ __align__(16) ushort As[8 * 512];
    __shared__ __align__(16) ushort Bs[8 * 512];
    const int tid = threadIdx.x;
    const int w = tid >> 6, lane = tid & 63;
    const int n0 = blockIdx.x * 128, m0 = blockIdx.y * 128;
    const int nkf = KE >> 5;
    const int KT = nkf / SPLITK;
    const int kt0 = blockIdx.z * KT;
    const int wm = w & 1, wn = w >> 1;
    const int c0 = 2 * w, c1 = c0 + 1;

    f32x4 acc[4][4] = {};

    const ushort* Ab0 = Af + ((size_t)(m0 / 16 + c0) * nkf) * 512 + lane * 8;
    const ushort* Ab1 = Af + ((size_t)(m0 / 16 + c1) * nkf) * 512 + lane * 8;
    const ushort* Bb0 = Bf + ((size_t)(n0 / 16 + c0) * nkf) * 512 + lane * 8;
    const ushort* Bb1 = Bf + ((size_t)(n0 / 16 + c1) * nkf) * 512 + lane * 8;
    ushort* As0 = As + c0 * 512 + lane * 8;
    ushort* As1 = As + c1 * 512 + lane * 8;
    ushort* Bs0 = Bs + c0 * 512 + lane * 8;
    ushort* Bs1 = Bs + c1 * 512 + lane * 8;

    for (int kt = kt0; kt < kt0 + KT; ++kt) {
        const size_t ko = (size_t)kt * 512;
        __builtin_amdgcn_global_load_lds((const __attribute__((address_space(1))) void*)(Ab0 + ko),
                                         (__attribute__((address_space(3))) void*)As0, 16, 0, 0);
        __builtin_amdgcn_global_load_lds((const __attribute__((address_space(1))) void*)(Ab1 + ko),
                                         (__attribute__((address_space(3))) void*)As1, 16, 0, 0);
        __builtin_amdgcn_global_load_lds((const __attribute__((address_space(1))) void*)(Bb0 + ko),
                                         (__attribute__((address_space(3))) void*)Bs0, 16, 0, 0);
        __builtin_amdgcn_global_load_lds((const __attribute__((address_space(1))) void*)(Bb1 + ko),
                                         (__attribute__((address_space(3))) void*)Bs1, 16, 0, 0);
        __syncthreads();
        short8 av[4], bv[4];
#pragma unroll
        for (int i = 0; i < 4; ++i)
            av[i] = *(const short8*)&As[(wm * 4 + i) * 512 + lane * 8];
#pragma unroll
        for (int i = 0; i < 4; ++i)
            bv[i] = *(const short8*)&Bs[(wn * 4 + i) * 512 + lane * 8];
#pragma unroll
        for (int mi = 0; mi < 4; ++mi)
#pragma unroll
            for (int ni = 0; ni < 4; ++ni)
                acc[mi][ni] = __builtin_amdgcn_mfma_f32_16x16x32_bf16(av[mi], bv[ni],
                                                                      acc[mi][ni], 0, 0, 0);
        __syncthreads();
    }

    // C/D layout (m89-verified): col = lane&15, row = (lane>>4)*4 + reg
    float* Cw = C + (size_t)blockIdx.z * ((size_t)M * N);
    const int r0 = (lane >> 4) * 4, cc = lane & 15;
#pragma unroll
    for (int mi = 0; mi < 4; ++mi)
#pragma unroll
        for (int r = 0; r < 4; ++r) {
            const int row = m0 + wm * 64 + mi * 16 + r0 + r;
            float* crow = &Cw[(size_t)row * N + n0 + wn * 64 + cc];
#pragma unroll
            for (int ni = 0; ni < 4; ++ni) crow[ni * 16] = acc[mi][ni][r];
        }
}

// sum 4 M*N slabs (float4)
__global__ __launch_bounds__(256) void k_red4(const float* __restrict__ p,
                                              float* __restrict__ o, int n4) {
    int i = blockIdx.x * 256 + threadIdx.x;
    const float4* p4 = (const float4*)p;
    float4 a = p4[i], b = p4[i + n4], c = p4[i + 2 * n4], d = p4[i + 3 * n4];
    ((float4*)o)[i] = make_float4(a.x + b.x + c.x + d.x, a.y + b.y + c.y + d.y,
                                  a.z + b.z + c.z + d.z, a.w + b.w + c.w + d.w);
}

// ---------------- depthwise causal conv (D_CONV=4) + bias + SiLU ----------------
__global__ void k_conv_silu(const float* __restrict__ xz, const float* __restrict__ cw,
                            const float* __restrict__ cb, float* __restrict__ u) {
    int idx = blockIdx.x * blockDim.x + threadIdx.x;
    int c  = idx & (DINNER - 1);
    int bl = idx >> 9;
    int l  = bl & (LL - 1);
    float acc = cb[c];
#pragma unroll
    for (int k = 0; k < DCONV; ++k) {
        int t = l - (DCONV - 1) + k;
        if (t >= 0) acc += cw[c * DCONV + k] * xz[(size_t)(bl - (DCONV - 1) + k) * 2 * DINNER + c];
    }
    u[(size_t)idx] = acc * sigmoidf_(acc);
}

// ---------------- fused x_proj + delta (LDS-staged w_xp, 2-token reuse) ----------------
// block = 256 threads over 16 tokens: mp = tid>>5 (token pair), jg = (tid>>3)&3
// (12-col group), s = tid&7 (k-slice). w_xp staged in LDS in 4 chunks of 128
// rows; each w4 read feeds FMAs for 2 tokens. grid = BL/16 = 512 blocks.
__global__ __launch_bounds__(256) void k_xpd(const float* __restrict__ u,
                                             const float* __restrict__ w_xp,
                                             const float* __restrict__ w_dt,
                                             const float* __restrict__ b_dt,
                                             float* __restrict__ Bm,
                                             float* __restrict__ Cm,
                                             float* __restrict__ delta) {
    const int tid = threadIdx.x;
    const int bl0 = blockIdx.x * 16;
    __shared__ float us[16 * DINNER];   // 32 KB
    __shared__ float wsx[128 * 48];     // 24 KB (one chunk of w_xp)
    __shared__ float dts[16][DTRANK];   // 1 KB

    {   // cooperative coalesced load of 16 tokens of u (8192 floats)
        const float4* u4 = (const float4*)&u[(size_t)bl0 * DINNER];
        float4* us4 = (float4*)us;
#pragma unroll
        for (int q = 0; q < 8; ++q) us4[tid + q * 256] = u4[tid + q * 256];
    }

    const int mp = tid >> 5;
    const int jg = (tid >> 3) & 3;
    const int s  = tid & 7;
    const float* usm0 = &us[(mp * 2 + 0) * DINNER];
    const float* usm1 = &us[(mp * 2 + 1) * DINNER];

    float acc0[12] = {}, acc1[12] = {};
#pragma unroll 1
    for (int ck = 0; ck < 4; ++ck) {
        __syncthreads();   // us ready (ck=0); wsx consumers done (ck>0)
        {   // stage w_xp rows [ck*128, ck*128+128): 1536 float4
            const float4* wg = (const float4*)&w_xp[ck * 128 * 48];
            float4* wl = (float4*)wsx;
#pragma unroll
            for (int q = 0; q < 6; ++q) wl[tid + q * 256] = wg[tid + q * 256];
        }
        __syncthreads();
#pragma unroll
        for (int i = 0; i < 16; ++i) {
            const int kl = i * 8 + s;
            const float a0 = usm0[ck * 128 + kl];
            const float a1 = usm1[ck * 128 + kl];
            const float* wr = &wsx[kl * 48 + jg * 12];
            float4 w0 = *(const float4*)&wr[0];
            float4 w1 = *(const float4*)&wr[4];
            float4 w2 = *(const float4*)&wr[8];
            acc0[0]  = fmaf(a0, w0.x, acc0[0]);  acc1[0]  = fmaf(a1, w0.x, acc1[0]);
            acc0[1]  = fmaf(a0, w0.y, acc0[1]);  acc1[1]  = fmaf(a1, w0.y, acc1[1]);
            acc0[2]  = fmaf(a0, w0.z, acc0[2]);  acc1[2]  = fmaf(a1, w0.z, acc1[2]);
            acc0[3]  = fmaf(a0, w0.w, acc0[3]);  acc1[3]  = fmaf(a1, w0.w, acc1[3]);
            acc0[4]  = fmaf(a0, w1.x, acc0[4]);  acc1[4]  = fmaf(a1, w1.x, acc1[4]);
            acc0[5]  = fmaf(a0, w1.y, acc0[5]);  acc1[5]  = fmaf(a1, w1.y, acc1[5]);
            acc0[6]  = fmaf(a0, w1.z, acc0[6]);  acc1[6]  = fmaf(a1, w1.z, acc1[6]);
            acc0[7]  = fmaf(a0, w1.w, acc0[7]);  acc1[7]  = fmaf(a1, w1.w, acc1[7]);
            acc0[8]  = fmaf(a0, w2.x, acc0[8]);  acc1[8]  = fmaf(a1, w2.x, acc1[8]);
            acc0[9]  = fmaf(a0, w2.y, acc0[9]);  acc1[9]  = fmaf(a1, w2.y, acc1[9]);
            acc0[10] = fmaf(a0, w2.z, acc0[10]); acc1[10] = fmaf(a1, w2.z, acc1[10]);
            acc0[11] = fmaf(a0, w2.w, acc0[11]); acc1[11] = fmaf(a1, w2.w, acc1[11]);
        }
    }
    // butterfly reduce across the 8 k-slice lanes
#pragma unroll
    for (int off = 4; off >= 1; off >>= 1) {
#pragma unroll
        for (int j = 0; j < 12; ++j) {
            acc0[j] += __shfl_xor(acc0[j], off, 8);
            acc1[j] += __shfl_xor(acc1[j], off, 8);
        }
    }
    if (s < 6) {
        const int bl_a = bl0 + mp * 2 + 0;
        const int bl_b = bl0 + mp * 2 + 1;
#pragma unroll
        for (int q = 0; q < 2; ++q) {
            int j = jg * 12 + s * 2 + q;
            float v0 = acc0[s * 2 + q];
            float v1 = acc1[s * 2 + q];
            if (j < 16) {
                dts[mp * 2 + 0][j] = v0;
                dts[mp * 2 + 1][j] = v1;
            } else if (j < 32) {
                Bm[(size_t)bl_a * DSTATE + (j - 16)] = v0;
                Bm[(size_t)bl_b * DSTATE + (j - 16)] = v1;
            } else {
                Cm[(size_t)bl_a * DSTATE + (j - 32)] = v0;
                Cm[(size_t)bl_b * DSTATE + (j - 32)] = v1;
            }
        }
    }
    __syncthreads();

    // phase 2: delta = softplus(dt @ w_dt + b_dt); thread: 4 channels x 8 tokens
    const int c0 = (tid & 127) * 4;
    const int mb = (tid >> 7) * 8;
    float4 bd = *(const float4*)&b_dt[c0];
    float a0[8], a1[8], a2[8], a3[8];
#pragma unroll
    for (int t = 0; t < 8; ++t) { a0[t] = bd.x; a1[t] = bd.y; a2[t] = bd.z; a3[t] = bd.w; }
#pragma unroll
    for (int r = 0; r < DTRANK; ++r) {
        float4 w4 = *(const float4*)&w_dt[r * DINNER + c0];
#pragma unroll
        for (int t = 0; t < 8; ++t) {
            float f = dts[mb + t][r];
            a0[t] = fmaf(f, w4.x, a0[t]);
            a1[t] = fmaf(f, w4.y, a1[t]);
            a2[t] = fmaf(f, w4.z, a2[t]);
            a3[t] = fmaf(f, w4.w, a3[t]);
        }
    }
#pragma unroll
    for (int t = 0; t < 8; ++t) {
        float4 o;
        o.x = (a0[t] > 20.f) ? a0[t] : log1pf(__expf(a0[t]));
        o.y = (a1[t] > 20.f) ? a1[t] : log1pf(__expf(a1[t]));
        o.z = (a2[t] > 20.f) ? a2[t] : log1pf(__expf(a2[t]));
        o.w = (a3[t] > 20.f) ? a3[t] : log1pf(__expf(a3[t]));
        *(float4*)&delta[(size_t)(bl0 + mb + t) * DINNER + c0] = o;
    }
}

// ---------------- chunked selective scan, per-channel 16-state-in-registers ----------------
__global__ __launch_bounds__(256) void k_scan_a(const float* __restrict__ delta,
                                                const float* __restrict__ u,
                                                const float* __restrict__ Bm,
                                                const float* __restrict__ A_log,
                                                float* __restrict__ aprod,
                                                float* __restrict__ hend) {
    const int tid = threadIdx.x;
    const int bid = blockIdx.x;
    const int chalf = bid & 1;
    const int k = (bid >> 1) & (NCHUNK - 1);
    const int b = bid >> 7;
    const int c = chalf * 256 + tid;
    const int bl0 = b * LL + k * LC;

    __shared__ float Bs[LC * DSTATE];
    for (int i = tid; i < LC * DSTATE; i += 256) Bs[i] = Bm[(size_t)bl0 * DSTATE + i];
    __syncthreads();

    float Ac[DSTATE];
#pragma unroll
    for (int q = 0; q < 4; ++q) {
        float4 a = *(const float4*)&A_log[c * DSTATE + q * 4];
        Ac[q * 4 + 0] = -__expf(a.x); Ac[q * 4 + 1] = -__expf(a.y);
        Ac[q * 4 + 2] = -__expf(a.z); Ac[q * 4 + 3] = -__expf(a.w);
    }

    float h[DSTATE] = {};
    float ap[DSTATE];
#pragma unroll
    for (int n = 0; n < DSTATE; ++n) ap[n] = 1.f;

    float dlt = delta[(size_t)bl0 * DINNER + c];
    float uu  = u[(size_t)bl0 * DINNER + c];
    for (int t = 0; t < LC; ++t) {
        float dlt2 = 0.f, uu2 = 0.f;
        if (t + 1 < LC) {
            dlt2 = delta[(size_t)(bl0 + t + 1) * DINNER + c];
            uu2  = u[(size_t)(bl0 + t + 1) * DINNER + c];
        }
        const float w = dlt * uu;
        const float4* Bs4 = (const float4*)&Bs[t * DSTATE];
        float4 b0 = Bs4[0], b1 = Bs4[1], b2 = Bs4[2], b3 = Bs4[3];
        float bv[DSTATE] = {b0.x, b0.y, b0.z, b0.w, b1.x, b1.y, b1.z, b1.w,
                            b2.x, b2.y, b2.z, b2.w, b3.x, b3.y, b3.z, b3.w};
#pragma unroll
        for (int n = 0; n < DSTATE; ++n) {
            float dA = __expf(dlt * Ac[n]);
            ap[n] *= dA;
            h[n] = fmaf(dA, h[n], w * bv[n]);
        }
        dlt = dlt2; uu = uu2;
    }
    size_t base = ((size_t)(k * BB + b) * DINNER + c) * DSTATE;
#pragma unroll
    for (int q = 0; q < 4; ++q) {
        *(float4*)&aprod[base + q * 4] = make_float4(ap[q*4], ap[q*4+1], ap[q*4+2], ap[q*4+3]);
        *(float4*)&hend[base + q * 4]  = make_float4(h[q*4],  h[q*4+1],  h[q*4+2],  h[q*4+3]);
    }
}

__global__ __launch_bounds__(256) void k_scan_b(const float* __restrict__ aprod,
                                                const float* __restrict__ hend,
                                                float* __restrict__ hstart) {
    int i = blockIdx.x * 256 + threadIdx.x;
    float h = 0.f;
#pragma unroll 4
    for (int k = 0; k < NCHUNK; ++k) {
        size_t idx = (size_t)k * NREC + i;
        float a = aprod[idx];
        float e = hend[idx];
        hstart[idx] = h;
        h = fmaf(a, h, e);
    }
}

__global__ __launch_bounds__(256) void k_scan_c(const float* __restrict__ delta,
                                                const float* __restrict__ u,
                                                const float* __restrict__ xz,
                                                const float* __restrict__ Bm,
                                                const float* __restrict__ Cm,
                                                const float* __restrict__ A_log,
                                                const float* __restrict__ Dp,
                                                const float* __restrict__ hstart,
                                                float* __restrict__ y) {
    const int tid = threadIdx.x;
    const int bid = blockIdx.x;
    const int chalf = bid & 1;
    const int k = (bid >> 1) & (NCHUNK - 1);
    const int b = bid >> 7;
    const int c = chalf * 256 + tid;
    const int bl0 = b * LL + k * LC;

    __shared__ float Bs[LC * DSTATE];
    __shared__ float Cs[LC * DSTATE];
    for (int i = tid; i < LC * DSTATE; i += 256) {
        Bs[i] = Bm[(size_t)bl0 * DSTATE + i];
        Cs[i] = Cm[(size_t)bl0 * DSTATE + i];
    }
    __syncthreads();

    float Ac[DSTATE];
#pragma unroll
    for (int q = 0; q < 4; ++q) {
        float4 a = *(const float4*)&A_log[c * DSTATE + q * 4];
        Ac[q * 4 + 0] = -__expf(a.x); Ac[q * 4 + 1] = -__expf(a.y);
        Ac[q * 4 + 2] = -__expf(a.z); Ac[q * 4 + 3] = -__expf(a.w);
    }
    const float Dc = Dp[c];

    float h[DSTATE];
    size_t hbase = ((size_t)(k * BB + b) * DINNER + c) * DSTATE;
#pragma unroll
    for (int q = 0; q < 4; ++q) {
        float4 hv = *(const float4*)&hstart[hbase + q * 4];
        h[q*4] = hv.x; h[q*4+1] = hv.y; h[q*4+2] = hv.z; h[q*4+3] = hv.w;
    }

    float dlt = delta[(size_t)bl0 * DINNER + c];
    float uu  = u[(size_t)bl0 * DINNER + c];
    float rr  = xz[(size_t)bl0 * 2 * DINNER + DINNER + c];
    for (int t = 0; t < LC; ++t) {
        float dlt2 = 0.f, uu2 = 0.f, rr2 = 0.f;
        if (t + 1 < LC) {
            dlt2 = delta[(size_t)(bl0 + t + 1) * DINNER + c];
            uu2  = u[(size_t)(bl0 + t + 1) * DINNER + c];
            rr2  = xz[(size_t)(bl0 + t + 1) * 2 * DINNER + DINNER + c];
        }
        const float w = dlt * uu;
        const float4* Bs4 = (const float4*)&Bs[t * DSTATE];
        float4 b0 = Bs4[0], b1 = Bs4[1], b2 = Bs4[2], b3 = Bs4[3];
        float bv[DSTATE] = {b0.x, b0.y, b0.z, b0.w, b1.x, b1.y, b1.z, b1.w,
                            b2.x, b2.y, b2.z, b2.w, b3.x, b3.y, b3.z, b3.w};
        const float4* Cs4 = (const float4*)&Cs[t * DSTATE];
        float4 c0 = Cs4[0], c1 = Cs4[1], c2 = Cs4[2], c3 = Cs4[3];
        float cv[DSTATE] = {c0.x, c0.y, c0.z, c0.w, c1.x, c1.y, c1.z, c1.w,
                            c2.x, c2.y, c2.z, c2.w, c3.x, c3.y, c3.z, c3.w};
        float s0 = 0.f, s1 = 0.f, s2 = 0.f, s3 = 0.f;
#pragma unroll
        for (int n = 0; n < DSTATE; n += 4) {
            float dA0 = __expf(dlt * Ac[n+0]);
            float dA1 = __expf(dlt * Ac[n+1]);
            float dA2 = __expf(dlt * Ac[n+2]);
            float dA3 = __expf(dlt * Ac[n+3]);
            h[n+0] = fmaf(dA0, h[n+0], w * bv[n+0]);
            h[n+1] = fmaf(dA1, h[n+1], w * bv[n+1]);
            h[n+2] = fmaf(dA2, h[n+2], w * bv[n+2]);
            h[n+3] = fmaf(dA3, h[n+3], w * bv[n+3]);
            s0 = fmaf(h[n+0], cv[n+0], s0);
            s1 = fmaf(h[n+1], cv[n+1], s1);
            s2 = fmaf(h[n+2], cv[n+2], s2);
            s3 = fmaf(h[n+3], cv[n+3], s3);
        }
        float yv = (s0 + s1) + (s2 + s3) + uu * Dc;
        y[(size_t)(bl0 + t) * DINNER + c] = yv * (rr * sigmoidf_(rr));
        dlt = dlt2; uu = uu2; rr = rr2;
    }
}

extern "C" void kernel_launch(void* const* d_in, const int* in_sizes, int n_in,
                              void* d_out, int out_size, void* d_ws, size_t ws_size,
                              hipStream_t stream) {
    const int*   ids   = (const int*)d_in[0];
    const float* emb   = (const float*)d_in[1];
    const float* w_in  = (const float*)d_in[2];
    const float* cw    = (const float*)d_in[3];
    const float* cb    = (const float*)d_in[4];
    const float* w_xp  = (const float*)d_in[5];
    const float* w_dt  = (const float*)d_in[6];
    const float* b_dt  = (const float*)d_in[7];
    const float* A_log = (const float*)d_in[8];
    const float* Dp    = (const float*)d_in[9];
    const float* w_out = (const float*)d_in[10];
    float* out = (float*)d_out;

    float* ws = (float*)d_ws;
    float* x    = ws;                              // BL*256  = 2.10M floats
    float* xz   = x  + (size_t)BL * DMODEL;        // BL*1024 = 8.39M (also split-K partials)
    float* u    = xz + (size_t)BL * 2 * DINNER;    // BL*512  = 4.19M (also y_frag bf16)
    float* Bm   = u  + (size_t)BL * DINNER;        // BL*16
    float* Cm   = Bm + (size_t)BL * DSTATE;        // BL*16
    float* dlt  = Cm + (size_t)BL * DSTATE;        // BL*512
    float* y    = dlt + (size_t)BL * DINNER;       // BL*512
    float* hend = y + (size_t)BL * DINNER;         // 2.10M (also x_frag bf16)
    float* wfif = hend + (size_t)NCHUNK * NREC;    // 262144 floats (w_in frag)
    float* wfof = wfif + 262144;                   // 131072 floats (w_out frag)
    float* aprod  = x;     // overlays x (dead during scan)
    float* hstart = aprod; // scan_b is read-before-write per element
    ushort* xfrag = (ushort*)hend;  // alive cvt->in_proj only; scan_a writes hend later
    ushort* yfrag = (ushort*)u;     // alive cvt->out_proj only; u dead after scan_c
    ushort* wfi = (ushort*)wfif;
    ushort* wfo = (ushort*)wfof;

    for (int l = 0; l < NLAYER; ++l) {
        // ---- in_proj: xz = A @ w_in via split-bf16 MFMA (A = emb-gather for l==0)
        if (l == 0)
            k_cvt_a<DMODEL, true><<<1024, 256, 0, stream>>>(x, xfrag, ids, emb);
        else
            k_cvt_a<DMODEL, false><<<1024, 256, 0, stream>>>(x, xfrag, ids, emb);
        k_cvt_w<DMODEL><<<128, 256, 0, stream>>>(w_in + (size_t)l * DMODEL * 2 * DINNER,
                                                 wfi, 2 * DINNER);
        k_mgemm<1><<<dim3(2 * DINNER / 128, BL / 128, 1), 256, 0, stream>>>(
            xfrag, wfi, xz, BL, 2 * DINNER, 2 * DMODEL);

        k_conv_silu<<<(BL * DINNER) / 256, 256, 0, stream>>>(
            xz, cw + l * DINNER * DCONV, cb + l * DINNER, u);
        k_xpd<<<BL / 16, 256, 0, stream>>>(u, w_xp + (size_t)l * DINNER * 48,
                                           w_dt + (size_t)l * DTRANK * DINNER,
                                           b_dt + (size_t)l * DINNER, Bm, Cm, dlt);
        const float* Al = A_log + (size_t)l * DINNER * DSTATE;
        k_scan_a<<<BB * NCHUNK * 2, 256, 0, stream>>>(dlt, u, Bm, Al, aprod, hend);
        k_scan_b<<<NREC / 256, 256, 0, stream>>>(aprod, hend, hstart);
        k_scan_c<<<BB * NCHUNK * 2, 256, 0, stream>>>(dlt, u, xz, Bm, Cm, Al,
                                                      Dp + (size_t)l * DINNER, hstart, y);

        // ---- out_proj: dst = y @ w_out via split-bf16 MFMA, split-K=4 into xz
        k_cvt_a<DINNER, false><<<2048, 256, 0, stream>>>(y, yfrag, ids, emb);
        k_cvt_w<DINNER><<<64, 256, 0, stream>>>(w_out + (size_t)l * DINNER * DMODEL,
                                                wfo, DMODEL);
        float* dst = (l == NLAYER - 1) ? out : x;
        k_mgemm<4><<<dim3(DMODEL / 128, BL / 128, 4), 256, 0, stream>>>(
            yfrag, wfo, xz, BL, DMODEL, 2 * DINNER);
        k_red4<<<(BL * DMODEL / 4) / 256, 256, 0, stream>>>(xz, dst, BL * DMODEL / 4);
    }
}

// Round 10
// 288.234 us; speedup vs baseline: 2.1123x; 1.1647x over previous
//
#include <hip/hip_runtime.h>
#include <math.h>

#define NLAYER 2
#define DMODEL 256
#define DINNER 512
#define DSTATE 16
#define DTRANK 16
#define DCONV  4
#define BB     4
#define LL     2048
#define BL     (BB*LL)
#define NCHUNK 64
#define LC     (LL/NCHUNK)          // 32
#define NREC   (BB*DINNER*DSTATE)   // 32768
#define VOCAB  256

typedef __attribute__((ext_vector_type(8))) short short8;   // 8 bf16 (4 VGPRs)
typedef __attribute__((ext_vector_type(4))) float f32x4;    // 4 fp32 acc

__device__ __forceinline__ float sigmoidf_(float x) { return 1.0f / (1.0f + __expf(-x)); }

// fp32 -> bf16 round-to-nearest-even (bit pattern) and back
__device__ __forceinline__ unsigned f2bf(float a) {
    unsigned u = __builtin_bit_cast(unsigned, a);
    return (u + 0x7fffu + ((u >> 16) & 1u)) >> 16;
}
__device__ __forceinline__ float bf2f(unsigned h) {
    return __builtin_bit_cast(float, h << 16);
}

// ---------------- embedding -> bf16 hi|lo table [VOCAB][2*DMODEL] ----------------
__global__ __launch_bounds__(256) void k_cvt_emb(const float* __restrict__ emb,
                                                 ushort* __restrict__ embf) {
    const int v = blockIdx.x;
    const int c = threadIdx.x;
    float s = emb[(size_t)v * DMODEL + c];
    unsigned hi = f2bf(s);
    unsigned lo = f2bf(s - bf2f(hi));
    embf[(size_t)v * (2 * DMODEL) + c] = (ushort)hi;
    embf[(size_t)v * (2 * DMODEL) + DMODEL + c] = (ushort)lo;
}

// ---------------- weight fp32 [K,N] -> frag bf16 hi/lo ----------------
// frag layout: [N/16][2K/32][64][8]; lane l holds B[kf*32+(l>>4)*8+j][nf*16+(l&15)]
template<int K>
__global__ __launch_bounds__(256) void k_cvt_w(const float* __restrict__ W,
                                               ushort* __restrict__ F, int N) {
    constexpr int NKF = K / 32;
    const int t = blockIdx.x * 256 + threadIdx.x;
    const int l = t & 63;
    const int cid = t >> 6;
    const int kf = cid % NKF;
    const int nf = cid / NKF;
    const int col = nf * 16 + (l & 15);
    const int k0 = kf * 32 + (l >> 4) * 8;
    float s[8];
#pragma unroll
    for (int j = 0; j < 8; ++j) s[j] = W[(size_t)(k0 + j) * N + col];
    unsigned hi[8], lo[8];
#pragma unroll
    for (int j = 0; j < 8; ++j) {
        hi[j] = f2bf(s[j]);
        lo[j] = f2bf(s[j] - bf2f(hi[j]));
    }
    uint4 ph = make_uint4(hi[0] | (hi[1] << 16), hi[2] | (hi[3] << 16),
                          hi[4] | (hi[5] << 16), hi[6] | (hi[7] << 16));
    uint4 pl = make_uint4(lo[0] | (lo[1] << 16), lo[2] | (lo[3] << 16),
                          lo[4] | (lo[5] << 16), lo[6] | (lo[7] << 16));
    size_t ohi = ((size_t)nf * (2 * NKF) + kf) * 512 + l * 8;
    *(uint4*)&F[ohi] = ph;
    *(uint4*)&F[ohi + (size_t)NKF * 512] = pl;
}

// ---------------- bf16 MFMA GEMM: A row-major bf16 [M][KE] (per-lane gather), B frag ----------------
// tile 128x128, 256 thr = 4 waves (2x2), per-wave 64x64.
// IDS: A is embf [VOCAB][KE], row r -> embf[ids[r]].
// SPLITK>1: blockIdx.z picks K-slice, writes slab z of C.
template<int SPLITK, bool IDS>
__global__ __launch_bounds__(256) void k_mgemm(const ushort* __restrict__ A,
                                               const ushort* __restrict__ Bf,
                                               float* __restrict__ C,
                                               int M, int N, int KE,
                                               const int* __restrict__ ids) {
    __shared__ __align__(16) ushort As[8 * 512];
    __shared__ __align__(16) ushort Bs[8 * 512];
    const int tid = threadIdx.x;
    const int w = tid >> 6, lane = tid & 63;
    const int n0 = blockIdx.x * 128, m0 = blockIdx.y * 128;
    const int nkf = KE >> 5;
    const int KT = nkf / SPLITK;
    const int kt0 = blockIdx.z * KT;
    const int wm = w & 1, wn = w >> 1;
    const int c0 = 2 * w, c1 = c0 + 1;

    f32x4 acc[4][4] = {};

    int row0 = m0 + c0 * 16 + (lane & 15);
    int row1 = m0 + c1 * 16 + (lane & 15);
    if (IDS) { row0 = ids[row0]; row1 = ids[row1]; }
    const ushort* Ap0 = A + (size_t)row0 * KE + (lane >> 4) * 8;
    const ushort* Ap1 = A + (size_t)row1 * KE + (lane >> 4) * 8;
    const ushort* Bb0 = Bf + ((size_t)(n0 / 16 + c0) * nkf) * 512 + lane * 8;
    const ushort* Bb1 = Bf + ((size_t)(n0 / 16 + c1) * nkf) * 512 + lane * 8;
    ushort* As0 = As + c0 * 512 + lane * 8;
    ushort* As1 = As + c1 * 512 + lane * 8;
    ushort* Bs0 = Bs + c0 * 512 + lane * 8;
    ushort* Bs1 = Bs + c1 * 512 + lane * 8;

    for (int kt = kt0; kt < kt0 + KT; ++kt) {
        __builtin_amdgcn_global_load_lds((const __attribute__((address_space(1))) void*)(Ap0 + kt * 32),
                                         (__attribute__((address_space(3))) void*)As0, 16, 0, 0);
        __builtin_amdgcn_global_load_lds((const __attribute__((address_space(1))) void*)(Ap1 + kt * 32),
                                         (__attribute__((address_space(3))) void*)As1, 16, 0, 0);
        __builtin_amdgcn_global_load_lds((const __attribute__((address_space(1))) void*)(Bb0 + (size_t)kt * 512),
                                         (__attribute__((address_space(3))) void*)Bs0, 16, 0, 0);
        __builtin_amdgcn_global_load_lds((const __attribute__((address_space(1))) void*)(Bb1 + (size_t)kt * 512),
                                         (__attribute__((address_space(3))) void*)Bs1, 16, 0, 0);
        __syncthreads();
        short8 av[4], bv[4];
#pragma unroll
        for (int i = 0; i < 4; ++i)
            av[i] = *(const short8*)&As[(wm * 4 + i) * 512 + lane * 8];
#pragma unroll
        for (int i = 0; i < 4; ++i)
            bv[i] = *(const short8*)&Bs[(wn * 4 + i) * 512 + lane * 8];
#pragma unroll
        for (int mi = 0; mi < 4; ++mi)
#pragma unroll
            for (int ni = 0; ni < 4; ++ni)
                acc[mi][ni] = __builtin_amdgcn_mfma_f32_16x16x32_bf16(av[mi], bv[ni],
                                                                      acc[mi][ni], 0, 0, 0);
        __syncthreads();
    }

    // C/D layout (m89-verified): col = lane&15, row = (lane>>4)*4 + reg
    float* Cw = C + (size_t)blockIdx.z * ((size_t)M * N);
    const int r0 = (lane >> 4) * 4, cc = lane & 15;
#pragma unroll
    for (int mi = 0; mi < 4; ++mi)
#pragma unroll
        for (int r = 0; r < 4; ++r) {
            const int row = m0 + wm * 64 + mi * 16 + r0 + r;
            float* crow = &Cw[(size_t)row * N + n0 + wn * 64 + cc];
#pragma unroll
            for (int ni = 0; ni < 4; ++ni) crow[ni * 16] = acc[mi][ni][r];
        }
}

// sum 4 M*N slabs; TOBF: write bf16 hi|lo row-major [BL][2*DMODEL] instead of fp32
template<bool TOBF>
__global__ __launch_bounds__(256) void k_red4(const float* __restrict__ p,
                                              float* __restrict__ o,
                                              ushort* __restrict__ xb, int n4) {
    int i = blockIdx.x * 256 + threadIdx.x;
    const float4* p4 = (const float4*)p;
    float4 a = p4[i], b = p4[i + n4], c = p4[i + 2 * n4], d = p4[i + 3 * n4];
    float4 r = make_float4(a.x + b.x + c.x + d.x, a.y + b.y + c.y + d.y,
                           a.z + b.z + c.z + d.z, a.w + b.w + c.w + d.w);
    if (TOBF) {
        const int e0 = i * 4;
        const int bl = e0 >> 8;
        const int cl = e0 & 255;
        float s[4] = {r.x, r.y, r.z, r.w};
        unsigned hi[4], lo[4];
#pragma unroll
        for (int j = 0; j < 4; ++j) {
            hi[j] = f2bf(s[j]);
            lo[j] = f2bf(s[j] - bf2f(hi[j]));
        }
        *(uint2*)&xb[(size_t)bl * 512 + cl] =
            make_uint2(hi[0] | (hi[1] << 16), hi[2] | (hi[3] << 16));
        *(uint2*)&xb[(size_t)bl * 512 + 256 + cl] =
            make_uint2(lo[0] | (lo[1] << 16), lo[2] | (lo[3] << 16));
    } else {
        ((float4*)o)[i] = r;
    }
}

// ---------------- fused conv+SiLU + x_proj + delta ----------------
// block = 256 threads over 16 tokens. Phase 0: depthwise causal conv (D_CONV=4)
// + bias + SiLU computed from xz into us[] (LDS) and u (global). Phase 1: x_proj
// with LDS-staged w_xp, 2-token register reuse. Phase 2: delta = softplus(dt@w_dt+b).
__global__ __launch_bounds__(256) void k_xpd(const float* __restrict__ xz,
                                             const float* __restrict__ cw,
                                             const float* __restrict__ cb,
                                             const float* __restrict__ w_xp,
                                             const float* __restrict__ w_dt,
                                             const float* __restrict__ b_dt,
                                             float* __restrict__ u,
                                             float* __restrict__ Bm,
                                             float* __restrict__ Cm,
                                             float* __restrict__ delta) {
    const int tid = threadIdx.x;
    const int bl0 = blockIdx.x * 16;
    __shared__ float us[16 * DINNER];   // 32 KB
    __shared__ float wsx[128 * 48];     // 24 KB (one chunk of w_xp)
    __shared__ float dts[16][DTRANK];   // 1 KB

    // ---- phase 0: conv + SiLU for 16 tokens (each thread: channels tid, tid+256)
    {
        const int ch0 = tid, ch1 = 256 + tid;
        float4 cwA = *(const float4*)&cw[ch0 * 4];
        float4 cwB = *(const float4*)&cw[ch1 * 4];
        const float cbA = cb[ch0], cbB = cb[ch1];
        const int lbase = bl0 & (LL - 1);
#pragma unroll
        for (int m = 0; m < 16; ++m) {
            const int bl = bl0 + m;
            const int lpos = lbase + m;
            float aA = cbA, aB = cbB;
#pragma unroll
            for (int k = 0; k < DCONV; ++k) {
                int tt = lpos - (DCONV - 1) + k;
                if (tt >= 0) {
                    const float* xr = &xz[(size_t)(bl - (DCONV - 1) + k) * 2 * DINNER];
                    aA = fmaf(((const float*)&cwA)[k], xr[ch0], aA);
                    aB = fmaf(((const float*)&cwB)[k], xr[ch1], aB);
                }
            }
            float uA = aA * sigmoidf_(aA);
            float uB = aB * sigmoidf_(aB);
            us[m * DINNER + ch0] = uA;
            us[m * DINNER + ch1] = uB;
            u[(size_t)bl * DINNER + ch0] = uA;
            u[(size_t)bl * DINNER + ch1] = uB;
        }
    }

    const int mp = tid >> 5;
    const int jg = (tid >> 3) & 3;
    const int s  = tid & 7;
    const float* usm0 = &us[(mp * 2 + 0) * DINNER];
    const float* usm1 = &us[(mp * 2 + 1) * DINNER];

    float acc0[12] = {}, acc1[12] = {};
#pragma unroll 1
    for (int ck = 0; ck < 4; ++ck) {
        __syncthreads();   // us ready (ck=0); wsx consumers done (ck>0)
        {   // stage w_xp rows [ck*128, ck*128+128): 1536 float4
            const float4* wg = (const float4*)&w_xp[ck * 128 * 48];
            float4* wl = (float4*)wsx;
#pragma unroll
            for (int q = 0; q < 6; ++q) wl[tid + q * 256] = wg[tid + q * 256];
        }
        __syncthreads();
#pragma unroll
        for (int i = 0; i < 16; ++i) {
            const int kl = i * 8 + s;
            const float a0 = usm0[ck * 128 + kl];
            const float a1 = usm1[ck * 128 + kl];
            const float* wr = &wsx[kl * 48 + jg * 12];
            float4 w0 = *(const float4*)&wr[0];
            float4 w1 = *(const float4*)&wr[4];
            float4 w2 = *(const float4*)&wr[8];
            acc0[0]  = fmaf(a0, w0.x, acc0[0]);  acc1[0]  = fmaf(a1, w0.x, acc1[0]);
            acc0[1]  = fmaf(a0, w0.y, acc0[1]);  acc1[1]  = fmaf(a1, w0.y, acc1[1]);
            acc0[2]  = fmaf(a0, w0.z, acc0[2]);  acc1[2]  = fmaf(a1, w0.z, acc1[2]);
            acc0[3]  = fmaf(a0, w0.w, acc0[3]);  acc1[3]  = fmaf(a1, w0.w, acc1[3]);
            acc0[4]  = fmaf(a0, w1.x, acc0[4]);  acc1[4]  = fmaf(a1, w1.x, acc1[4]);
            acc0[5]  = fmaf(a0, w1.y, acc0[5]);  acc1[5]  = fmaf(a1, w1.y, acc1[5]);
            acc0[6]  = fmaf(a0, w1.z, acc0[6]);  acc1[6]  = fmaf(a1, w1.z, acc1[6]);
            acc0[7]  = fmaf(a0, w1.w, acc0[7]);  acc1[7]  = fmaf(a1, w1.w, acc1[7]);
            acc0[8]  = fmaf(a0, w2.x, acc0[8]);  acc1[8]  = fmaf(a1, w2.x, acc1[8]);
            acc0[9]  = fmaf(a0, w2.y, acc0[9]);  acc1[9]  = fmaf(a1, w2.y, acc1[9]);
            acc0[10] = fmaf(a0, w2.z, acc0[10]); acc1[10] = fmaf(a1, w2.z, acc1[10]);
            acc0[11] = fmaf(a0, w2.w, acc0[11]); acc1[11] = fmaf(a1, w2.w, acc1[11]);
        }
    }
    // butterfly reduce across the 8 k-slice lanes
#pragma unroll
    for (int off = 4; off >= 1; off >>= 1) {
#pragma unroll
        for (int j = 0; j < 12; ++j) {
            acc0[j] += __shfl_xor(acc0[j], off, 8);
            acc1[j] += __shfl_xor(acc1[j], off, 8);
        }
    }
    if (s < 6) {
        const int bl_a = bl0 + mp * 2 + 0;
        const int bl_b = bl0 + mp * 2 + 1;
#pragma unroll
        for (int q = 0; q < 2; ++q) {
            int j = jg * 12 + s * 2 + q;
            float v0 = acc0[s * 2 + q];
            float v1 = acc1[s * 2 + q];
            if (j < 16) {
                dts[mp * 2 + 0][j] = v0;
                dts[mp * 2 + 1][j] = v1;
            } else if (j < 32) {
                Bm[(size_t)bl_a * DSTATE + (j - 16)] = v0;
                Bm[(size_t)bl_b * DSTATE + (j - 16)] = v1;
            } else {
                Cm[(size_t)bl_a * DSTATE + (j - 32)] = v0;
                Cm[(size_t)bl_b * DSTATE + (j - 32)] = v1;
            }
        }
    }
    __syncthreads();

    // phase 2: delta = softplus(dt @ w_dt + b_dt); thread: 4 channels x 8 tokens
    const int c0 = (tid & 127) * 4;
    const int mb = (tid >> 7) * 8;
    float4 bd = *(const float4*)&b_dt[c0];
    float a0[8], a1[8], a2[8], a3[8];
#pragma unroll
    for (int t = 0; t < 8; ++t) { a0[t] = bd.x; a1[t] = bd.y; a2[t] = bd.z; a3[t] = bd.w; }
#pragma unroll
    for (int r = 0; r < DTRANK; ++r) {
        float4 w4 = *(const float4*)&w_dt[r * DINNER + c0];
#pragma unroll
        for (int t = 0; t < 8; ++t) {
            float f = dts[mb + t][r];
            a0[t] = fmaf(f, w4.x, a0[t]);
            a1[t] = fmaf(f, w4.y, a1[t]);
            a2[t] = fmaf(f, w4.z, a2[t]);
            a3[t] = fmaf(f, w4.w, a3[t]);
        }
    }
#pragma unroll
    for (int t = 0; t < 8; ++t) {
        float4 o;
        o.x = (a0[t] > 20.f) ? a0[t] : log1pf(__expf(a0[t]));
        o.y = (a1[t] > 20.f) ? a1[t] : log1pf(__expf(a1[t]));
        o.z = (a2[t] > 20.f) ? a2[t] : log1pf(__expf(a2[t]));
        o.w = (a3[t] > 20.f) ? a3[t] : log1pf(__expf(a3[t]));
        *(float4*)&delta[(size_t)(bl0 + mb + t) * DINNER + c0] = o;
    }
}

// ---------------- chunked selective scan, per-channel 16-state-in-registers ----------------
__global__ __launch_bounds__(256) void k_scan_a(const float* __restrict__ delta,
                                                const float* __restrict__ u,
                                                const float* __restrict__ Bm,
                                                const float* __restrict__ A_log,
                                                float* __restrict__ aprod,
                                                float* __restrict__ hend) {
    const int tid = threadIdx.x;
    const int bid = blockIdx.x;
    const int chalf = bid & 1;
    const int k = (bid >> 1) & (NCHUNK - 1);
    const int b = bid >> 7;
    const int c = chalf * 256 + tid;
    const int bl0 = b * LL + k * LC;

    __shared__ float Bs[LC * DSTATE];
    for (int i = tid; i < LC * DSTATE; i += 256) Bs[i] = Bm[(size_t)bl0 * DSTATE + i];
    __syncthreads();

    float Ac[DSTATE];
#pragma unroll
    for (int q = 0; q < 4; ++q) {
        float4 a = *(const float4*)&A_log[c * DSTATE + q * 4];
        Ac[q * 4 + 0] = -__expf(a.x); Ac[q * 4 + 1] = -__expf(a.y);
        Ac[q * 4 + 2] = -__expf(a.z); Ac[q * 4 + 3] = -__expf(a.w);
    }

    float h[DSTATE] = {};
    float ap[DSTATE];
#pragma unroll
    for (int n = 0; n < DSTATE; ++n) ap[n] = 1.f;

    float dlt = delta[(size_t)bl0 * DINNER + c];
    float uu  = u[(size_t)bl0 * DINNER + c];
    for (int t = 0; t < LC; ++t) {
        float dlt2 = 0.f, uu2 = 0.f;
        if (t + 1 < LC) {
            dlt2 = delta[(size_t)(bl0 + t + 1) * DINNER + c];
            uu2  = u[(size_t)(bl0 + t + 1) * DINNER + c];
        }
        const float w = dlt * uu;
        const float4* Bs4 = (const float4*)&Bs[t * DSTATE];
        float4 b0 = Bs4[0], b1 = Bs4[1], b2 = Bs4[2], b3 = Bs4[3];
        float bv[DSTATE] = {b0.x, b0.y, b0.z, b0.w, b1.x, b1.y, b1.z, b1.w,
                            b2.x, b2.y, b2.z, b2.w, b3.x, b3.y, b3.z, b3.w};
#pragma unroll
        for (int n = 0; n < DSTATE; ++n) {
            float dA = __expf(dlt * Ac[n]);
            ap[n] *= dA;
            h[n] = fmaf(dA, h[n], w * bv[n]);
        }
        dlt = dlt2; uu = uu2;
    }
    size_t base = ((size_t)(k * BB + b) * DINNER + c) * DSTATE;
#pragma unroll
    for (int q = 0; q < 4; ++q) {
        *(float4*)&aprod[base + q * 4] = make_float4(ap[q*4], ap[q*4+1], ap[q*4+2], ap[q*4+3]);
        *(float4*)&hend[base + q * 4]  = make_float4(h[q*4],  h[q*4+1],  h[q*4+2],  h[q*4+3]);
    }
}

__global__ __launch_bounds__(256) void k_scan_b(const float* __restrict__ aprod,
                                                const float* __restrict__ hend,
                                                float* __restrict__ hstart) {
    int i = blockIdx.x * 256 + threadIdx.x;
    float h = 0.f;
#pragma unroll 4
    for (int k = 0; k < NCHUNK; ++k) {
        size_t idx = (size_t)k * NREC + i;
        float a = aprod[idx];
        float e = hend[idx];
        hstart[idx] = h;
        h = fmaf(a, h, e);
    }
}

// Pass C: re-scan chunk, emit gated output as bf16 hi|lo row-major [BL][2*DINNER]
__global__ __launch_bounds__(256) void k_scan_c(const float* __restrict__ delta,
                                                const float* __restrict__ u,
                                                const float* __restrict__ xz,
                                                const float* __restrict__ Bm,
                                                const float* __restrict__ Cm,
                                                const float* __restrict__ A_log,
                                                const float* __restrict__ Dp,
                                                const float* __restrict__ hstart,
                                                ushort* __restrict__ yb) {
    const int tid = threadIdx.x;
    const int bid = blockIdx.x;
    const int chalf = bid & 1;
    const int k = (bid >> 1) & (NCHUNK - 1);
    const int b = bid >> 7;
    const int c = chalf * 256 + tid;
    const int bl0 = b * LL + k * LC;

    __shared__ float Bs[LC * DSTATE];
    __shared__ float Cs[LC * DSTATE];
    for (int i = tid; i < LC * DSTATE; i += 256) {
        Bs[i] = Bm[(size_t)bl0 * DSTATE + i];
        Cs[i] = Cm[(size_t)bl0 * DSTATE + i];
    }
    __syncthreads();

    float Ac[DSTATE];
#pragma unroll
    for (int q = 0; q < 4; ++q) {
        float4 a = *(const float4*)&A_log[c * DSTATE + q * 4];
        Ac[q * 4 + 0] = -__expf(a.x); Ac[q * 4 + 1] = -__expf(a.y);
        Ac[q * 4 + 2] = -__expf(a.z); Ac[q * 4 + 3] = -__expf(a.w);
    }
    const float Dc = Dp[c];

    float h[DSTATE];
    size_t hbase = ((size_t)(k * BB + b) * DINNER + c) * DSTATE;
#pragma unroll
    for (int q = 0; q < 4; ++q) {
        float4 hv = *(const float4*)&hstart[hbase + q * 4];
        h[q*4] = hv.x; h[q*4+1] = hv.y; h[q*4+2] = hv.z; h[q*4+3] = hv.w;
    }

    float dlt = delta[(size_t)bl0 * DINNER + c];
    float uu  = u[(size_t)bl0 * DINNER + c];
    float rr  = xz[(size_t)bl0 * 2 * DINNER + DINNER + c];
    for (int t = 0; t < LC; ++t) {
        float dlt2 = 0.f, uu2 = 0.f, rr2 = 0.f;
        if (t + 1 < LC) {
            dlt2 = delta[(size_t)(bl0 + t + 1) * DINNER + c];
            uu2  = u[(size_t)(bl0 + t + 1) * DINNER + c];
            rr2  = xz[(size_t)(bl0 + t + 1) * 2 * DINNER + DINNER + c];
        }
        const float w = dlt * uu;
        const float4* Bs4 = (const float4*)&Bs[t * DSTATE];
        float4 b0 = Bs4[0], b1 = Bs4[1], b2 = Bs4[2], b3 = Bs4[3];
        float bv[DSTATE] = {b0.x, b0.y, b0.z, b0.w, b1.x, b1.y, b1.z, b1.w,
                            b2.x, b2.y, b2.z, b2.w, b3.x, b3.y, b3.z, b3.w};
        const float4* Cs4 = (const float4*)&Cs[t * DSTATE];
        float4 c0 = Cs4[0], c1 = Cs4[1], c2 = Cs4[2], c3 = Cs4[3];
        float cv[DSTATE] = {c0.x, c0.y, c0.z, c0.w, c1.x, c1.y, c1.z, c1.w,
                            c2.x, c2.y, c2.z, c2.w, c3.x, c3.y, c3.z, c3.w};
        float s0 = 0.f, s1 = 0.f, s2 = 0.f, s3 = 0.f;
#pragma unroll
        for (int n = 0; n < DSTATE; n += 4) {
            float dA0 = __expf(dlt * Ac[n+0]);
            float dA1 = __expf(dlt * Ac[n+1]);
            float dA2 = __expf(dlt * Ac[n+2]);
            float dA3 = __expf(dlt * Ac[n+3]);
            h[n+0] = fmaf(dA0, h[n+0], w * bv[n+0]);
            h[n+1] = fmaf(dA1, h[n+1], w * bv[n+1]);
            h[n+2] = fmaf(dA2, h[n+2], w * bv[n+2]);
            h[n+3] = fmaf(dA3, h[n+3], w * bv[n+3]);
            s0 = fmaf(h[n+0], cv[n+0], s0);
            s1 = fmaf(h[n+1], cv[n+1], s1);
            s2 = fmaf(h[n+2], cv[n+2], s2);
            s3 = fmaf(h[n+3], cv[n+3], s3);
        }
        float yv = (s0 + s1) + (s2 + s3) + uu * Dc;
        float yg = yv * (rr * sigmoidf_(rr));
        unsigned hi = f2bf(yg);
        unsigned lo = f2bf(yg - bf2f(hi));
        yb[(size_t)(bl0 + t) * (2 * DINNER) + c] = (ushort)hi;
        yb[(size_t)(bl0 + t) * (2 * DINNER) + DINNER + c] = (ushort)lo;
        dlt = dlt2; uu = uu2; rr = rr2;
    }
}

extern "C" void kernel_launch(void* const* d_in, const int* in_sizes, int n_in,
                              void* d_out, int out_size, void* d_ws, size_t ws_size,
                              hipStream_t stream) {
    const int*   ids   = (const int*)d_in[0];
    const float* emb   = (const float*)d_in[1];
    const float* w_in  = (const float*)d_in[2];
    const float* cw    = (const float*)d_in[3];
    const float* cb    = (const float*)d_in[4];
    const float* w_xp  = (const float*)d_in[5];
    const float* w_dt  = (const float*)d_in[6];
    const float* b_dt  = (const float*)d_in[7];
    const float* A_log = (const float*)d_in[8];
    const float* Dp    = (const float*)d_in[9];
    const float* w_out = (const float*)d_in[10];
    float* out = (float*)d_out;

    float* ws = (float*)d_ws;
    float* x    = ws;                              // BL*256  floats (xb bf16 / aprod overlay)
    float* xz   = x  + (size_t)BL * DMODEL;        // BL*1024 (also split-K partials)
    float* u    = xz + (size_t)BL * 2 * DINNER;    // BL*512
    float* Bm   = u  + (size_t)BL * DINNER;        // BL*16
    float* Cm   = Bm + (size_t)BL * DSTATE;        // BL*16
    float* dlt  = Cm + (size_t)BL * DSTATE;        // BL*512
    float* y    = dlt + (size_t)BL * DINNER;       // BL*512 floats = yb bf16 [BL][1024]
    float* hend = y + (size_t)BL * DINNER;         // NCHUNK*NREC = 2.10M
    float* wfif = hend + (size_t)NCHUNK * NREC;    // 262144 floats (w_in frag)
    float* wfof = wfif + 262144;                   // 131072 floats (w_out frag)
    float* embff = wfof + 131072;                  // 65536 floats (emb bf16 table)
    // overlays: aprod/hstart use x region during scan (xb consumed by in_proj
    // mgemm before scan_a of the same layer overwrites; scan_b read-before-write)
    float* aprod  = x;
    float* hstart = aprod;
    ushort* xb   = (ushort*)x;      // [BL][512] hi|lo, written by red4<true> (layer 0)
    ushort* yb   = (ushort*)y;      // [BL][1024] hi|lo, written by scan_c
    ushort* wfi  = (ushort*)wfif;
    ushort* wfo  = (ushort*)wfof;
    ushort* embf = (ushort*)embff;  // [VOCAB][512] hi|lo

    k_cvt_emb<<<VOCAB, DMODEL, 0, stream>>>(emb, embf);

    for (int l = 0; l < NLAYER; ++l) {
        // ---- in_proj: xz = A @ w_in via split-bf16 MFMA (row-major A, per-lane gather)
        k_cvt_w<DMODEL><<<128, 256, 0, stream>>>(w_in + (size_t)l * DMODEL * 2 * DINNER,
                                                 wfi, 2 * DINNER);
        if (l == 0)
            k_mgemm<1, true><<<dim3(2 * DINNER / 128, BL / 128, 1), 256, 0, stream>>>(
                embf, wfi, xz, BL, 2 * DINNER, 2 * DMODEL, ids);
        else
            k_mgemm<1, false><<<dim3(2 * DINNER / 128, BL / 128, 1), 256, 0, stream>>>(
                xb, wfi, xz, BL, 2 * DINNER, 2 * DMODEL, ids);

        // ---- fused conv+silu + x_proj + delta
        k_xpd<<<BL / 16, 256, 0, stream>>>(xz, cw + l * DINNER * DCONV, cb + l * DINNER,
                                           w_xp + (size_t)l * DINNER * 48,
                                           w_dt + (size_t)l * DTRANK * DINNER,
                                           b_dt + (size_t)l * DINNER, u, Bm, Cm, dlt);

        const float* Al = A_log + (size_t)l * DINNER * DSTATE;
        k_scan_a<<<BB * NCHUNK * 2, 256, 0, stream>>>(dlt, u, Bm, Al, aprod, hend);
        k_scan_b<<<NREC / 256, 256, 0, stream>>>(aprod, hend, hstart);
        k_scan_c<<<BB * NCHUNK * 2, 256, 0, stream>>>(dlt, u, xz, Bm, Cm, Al,
                                                      Dp + (size_t)l * DINNER, hstart, yb);

        // ---- out_proj: dst = y @ w_out via split-bf16 MFMA, split-K=4 into xz
        k_cvt_w<DINNER><<<64, 256, 0, stream>>>(w_out + (size_t)l * DINNER * DMODEL,
                                                wfo, DMODEL);
        k_mgemm<4, false><<<dim3(DMODEL / 128, BL / 128, 4), 256, 0, stream>>>(
            yb, wfo, xz, BL, DMODEL, 2 * DINNER, ids);
        if (l == NLAYER - 1)
            k_red4<false><<<(BL * DMODEL / 4) / 256, 256, 0, stream>>>(xz, out, xb,
                                                                       BL * DMODEL / 4);
        else
            k_red4<true><<<(BL * DMODEL / 4) / 256, 256, 0, stream>>>(xz, out, xb,
                                                                      BL * DMODEL / 4);
    }
}